// Round 4
// baseline (775.608 us; speedup 1.0000x reference)
//
#include <hip/hip_runtime.h>

#define NSIG  65536
#define KAT   512
#define CDIM  64

__device__ __forceinline__ float bcastf(float v, int l) {
  return __int_as_float(__builtin_amdgcn_readlane(__float_as_int(v), l));
}
__device__ __forceinline__ unsigned umaxu(unsigned a, unsigned b) {
  return a > b ? a : b;
}
__device__ __forceinline__ unsigned dppmax(unsigned v, const int ctrl) {
  switch (ctrl) {
    case 0xB1:  return umaxu(v, (unsigned)__builtin_amdgcn_mov_dpp((int)v, 0xB1, 0xF, 0xF, true));
    case 0x4E:  return umaxu(v, (unsigned)__builtin_amdgcn_mov_dpp((int)v, 0x4E, 0xF, 0xF, true));
    case 0x124: return umaxu(v, (unsigned)__builtin_amdgcn_mov_dpp((int)v, 0x124, 0xF, 0xF, true));
    default:    return umaxu(v, (unsigned)__builtin_amdgcn_mov_dpp((int)v, 0x128, 0xF, 0xF, true));
  }
}

// G = D^T D  [512][512]; DT[k][c] = D[c][k]
__global__ void k_gram(const float* __restrict__ D, float* __restrict__ G,
                       float* __restrict__ DT) {
  int tid = blockIdx.x * 256 + threadIdx.x;      // 262144 total
  int i = tid >> 9, j = tid & 511;
  float acc = 0.f;
  #pragma unroll 8
  for (int c = 0; c < CDIM; ++c) acc = fmaf(D[c * KAT + i], D[c * KAT + j], acc);
  G[tid] = acc;
  if (tid < KAT * CDIM) {
    int k = tid >> 6, c = tid & 63;
    DT[tid] = D[c * KAT + k];
  }
}

// ST[n][b] = z_e[b][n%64][n/2048][(n/64)%32]   (signal-major staging)
__global__ void k_tr(const float* __restrict__ ze, float* __restrict__ st) {
  __shared__ float tile[64][33];
  int cz = blockIdx.x >> 5;
  int h  = blockIdx.x & 31;
  int t  = threadIdx.x;
  #pragma unroll
  for (int q = 0; q < 8; ++q) {
    int idx = q * 256 + t;
    int b = idx >> 5, w = idx & 31;
    tile[b][w] = ze[b * 65536 + cz * 1024 + h * 32 + w];
  }
  __syncthreads();
  #pragma unroll
  for (int q = 0; q < 8; ++q) {
    int idx = q * 256 + t;
    int w = idx >> 6, b = idx & 63;
    st[(h * 2048 + w * 64 + cz) * 64 + b] = tile[b][w];
  }
}

struct OmpState {
  float cr[8];      // residual correlations (this lane's 8 atoms)
  float Q[4][8];    // orthogonalized atom-correlation columns (Q~ = L^-1 G_I)
  float y[5];       // forward-solved RHS (incremental)
  float L10, L20, L21, L30, L31, L32, L40, L41, L42, L43;
  float d1, d2, d3, d4;   // inverse Cholesky diagonals
  int I[5];
  unsigned omega;
};

__device__ __forceinline__ void argmax_sel(const float* cr, unsigned omega, int lane,
                                           int& sl_o, int& jj_o) {
  unsigned ab[8];
  #pragma unroll
  for (int j = 0; j < 8; ++j) {
    unsigned a = __float_as_uint(cr[j]) & 0x7FFFFFFFu;
    ab[j] = ((omega >> j) & 1) ? a : 0u;
  }
  unsigned la = umaxu(umaxu(umaxu(ab[0], ab[1]), umaxu(ab[2], ab[3])),
                      umaxu(umaxu(ab[4], ab[5]), umaxu(ab[6], ab[7])));
  unsigned rmax = la;
  rmax = dppmax(rmax, 0xB1);
  rmax = dppmax(rmax, 0x4E);
  rmax = dppmax(rmax, 0x124);
  rmax = dppmax(rmax, 0x128);
  unsigned gmu = umaxu(
      umaxu((unsigned)__builtin_amdgcn_readlane((int)rmax, 0),
            (unsigned)__builtin_amdgcn_readlane((int)rmax, 16)),
      umaxu((unsigned)__builtin_amdgcn_readlane((int)rmax, 32),
            (unsigned)__builtin_amdgcn_readlane((int)rmax, 48)));
  unsigned long long ball = __ballot(la == gmu);
  int sl = __ffsll((long long)ball) - 1;         // lowest winning lane
  int jb = 7;
  jb = (ab[6] == gmu) ? 6 : jb;
  jb = (ab[5] == gmu) ? 5 : jb;
  jb = (ab[4] == gmu) ? 4 : jb;
  jb = (ab[3] == gmu) ? 3 : jb;
  jb = (ab[2] == gmu) ? 2 : jb;
  jb = (ab[1] == gmu) ? 1 : jb;
  jb = (ab[0] == gmu) ? 0 : jb;
  sl_o = sl;
  jj_o = __builtin_amdgcn_readlane(jb, sl) & 7;
}

__device__ __forceinline__ float extract8(const float* a, int jj, int sl) {
  float e = a[0];
  e = (jj == 1) ? a[1] : e; e = (jj == 2) ? a[2] : e;
  e = (jj == 3) ? a[3] : e; e = (jj == 4) ? a[4] : e;
  e = (jj == 5) ? a[5] : e; e = (jj == 6) ? a[6] : e;
  e = (jj == 7) ? a[7] : e;
  return bcastf(e, sl);
}

__device__ __forceinline__ void omp_step2(OmpState& S, int it, int khat, int sl, int jj,
                                          const float4& na, const float4& nb) {
  float w0 = 0.f, w1 = 0.f, w2 = 0.f, w3 = 0.f;
  if (it > 0) w0 = extract8(S.Q[0], jj, sl);
  if (it > 1) w1 = extract8(S.Q[1], jj, sl);
  if (it > 2) w2 = extract8(S.Q[2], jj, sl);
  if (it > 3) w3 = extract8(S.Q[3], jj, sl);
  float crv = extract8(S.cr, jj, sl);
  float s2 = 1.f - w0 * w0 - w1 * w1 - w2 * w2 - w3 * w3;
  float dn = (it == 0) ? 1.f : __builtin_amdgcn_rsqf(s2);
  float yn = crv * dn;                           // y_it = cr[khat] * d_it
  if (it == 0) { S.I[0] = khat; S.y[0] = yn; }
  if (it == 1) { S.I[1] = khat; S.y[1] = yn; S.L10 = w0; S.d1 = dn; }
  if (it == 2) { S.I[2] = khat; S.y[2] = yn; S.L20 = w0; S.L21 = w1; S.d2 = dn; }
  if (it == 3) { S.I[3] = khat; S.y[3] = yn; S.L30 = w0; S.L31 = w1; S.L32 = w2; S.d3 = dn; }
  if (it == 4) { S.I[4] = khat; S.y[4] = yn; S.L40 = w0; S.L41 = w1; S.L42 = w2; S.L43 = w3; S.d4 = dn; }
  if (it < 4) {
    float qn[8];
    qn[0] = na.x; qn[1] = na.y; qn[2] = na.z; qn[3] = na.w;
    qn[4] = nb.x; qn[5] = nb.y; qn[6] = nb.z; qn[7] = nb.w;
    #pragma unroll
    for (int j = 0; j < 8; ++j) {
      float q = qn[j];
      if (it > 0) q = fmaf(-w0, S.Q[0][j], q);
      if (it > 1) q = fmaf(-w1, S.Q[1][j], q);
      if (it > 2) q = fmaf(-w2, S.Q[2][j], q);
      qn[j] = q * dn;
    }
    #pragma unroll
    for (int u = 0; u < 4; ++u)
      if (u == it) {
        #pragma unroll
        for (int j = 0; j < 8; ++j) S.Q[u][j] = qn[j];
      }
    #pragma unroll
    for (int j = 0; j < 8; ++j) S.cr[j] = fmaf(-yn, qn[j], S.cr[j]);
  }
}

__device__ __forceinline__ float omp_fin(OmpState& S, const float* __restrict__ DT,
                                         float* __restrict__ out0,
                                         float* __restrict__ coeffs,
                                         int n, int lane, float zv) {
  float x4 = S.y[4] * S.d4;
  float x3 = (S.y[3] - S.L43 * x4) * S.d3;
  float x2 = (S.y[2] - S.L32 * x3 - S.L42 * x4) * S.d2;
  float x1 = (S.y[1] - S.L21 * x2 - S.L31 * x3 - S.L41 * x4) * S.d1;
  float x0 =  S.y[0] - S.L10 * x1 - S.L20 * x2 - S.L30 * x3 - S.L40 * x4;
  if (lane < 5) {
    int It = S.I[0]; float xt = x0;
    if (lane == 1) { It = S.I[1]; xt = x1; }
    if (lane == 2) { It = S.I[2]; xt = x2; }
    if (lane == 3) { It = S.I[3]; xt = x3; }
    if (lane == 4) { It = S.I[4]; xt = x4; }
    coeffs[(long)It * NSIG + n] = xt;
  }
  float rec = x0 * DT[S.I[0] * 64 + lane];
  rec = fmaf(x1, DT[S.I[1] * 64 + lane], rec);
  rec = fmaf(x2, DT[S.I[2] * 64 + lane], rec);
  rec = fmaf(x3, DT[S.I[3] * 64 + lane], rec);
  rec = fmaf(x4, DT[S.I[4] * 64 + lane], rec);
  const float d = rec - zv;
  const int offn = (n & 63) * 1024 + (n >> 11) * 32 + ((n >> 6) & 31);
  out0[lane * 65536 + offn] = zv + d;            // z + (z_dl - z), faithful
  return d * d;
}

#define ICUPD(S, c)                                                    \
  S.cr[0] = fmaf(d0.x, c, S.cr[0]); S.cr[1] = fmaf(d0.y, c, S.cr[1]);  \
  S.cr[2] = fmaf(d0.z, c, S.cr[2]); S.cr[3] = fmaf(d0.w, c, S.cr[3]);  \
  S.cr[4] = fmaf(d1.x, c, S.cr[4]); S.cr[5] = fmaf(d1.y, c, S.cr[5]);  \
  S.cr[6] = fmaf(d1.z, c, S.cr[6]); S.cr[7] = fmaf(d1.w, c, S.cr[7]);

#define RUN_PAIR(SA, SB, nA, nB, zvA, zvB)                              \
  {                                                                     \
    _Pragma("unroll 1")                                                 \
    for (int it = 0; it < 5; ++it) {                                    \
      int slA, jjA; argmax_sel(SA.cr, SA.omega, lane, slA, jjA);        \
      int slB, jjB; argmax_sel(SB.cr, SB.omega, lane, slB, jjB);        \
      const int khatA = (slA << 3) | jjA;                               \
      const int khatB = (slB << 3) | jjB;                               \
      if (lane == slA) SA.omega &= ~(1u << jjA);                        \
      if (lane == slB) SB.omega &= ~(1u << jjB);                        \
      float4 naA = {0,0,0,0}, nbA = {0,0,0,0};                          \
      float4 naB = {0,0,0,0}, nbB = {0,0,0,0};                          \
      if (it < 4) {                                                     \
        naA = *reinterpret_cast<const float4*>(G + khatA * KAT + 8 * lane);     \
        nbA = *reinterpret_cast<const float4*>(G + khatA * KAT + 8 * lane + 4); \
        naB = *reinterpret_cast<const float4*>(G + khatB * KAT + 8 * lane);     \
        nbB = *reinterpret_cast<const float4*>(G + khatB * KAT + 8 * lane + 4); \
      }                                                                 \
      omp_step2(SA, it, khatA, slA, jjA, naA, nbA);                     \
      omp_step2(SB, it, khatB, slB, jjB, naB, nbB);                     \
    }                                                                   \
    lossacc += omp_fin(SA, DT, out0, coeffs, nA, lane, zvA);            \
    lossacc += omp_fin(SB, DT, out0, coeffs, nB, lane, zvB);            \
  }

__global__ __launch_bounds__(256) void k_omp(
    const float* __restrict__ D, const float* __restrict__ G,
    const float* __restrict__ DT, const float* __restrict__ ST,
    float* __restrict__ out0, float* __restrict__ lossp,
    float* __restrict__ coeffs) {
  const int lane = threadIdx.x & 63;
  const int wid  = (blockIdx.x * 256 + threadIdx.x) >> 6;   // 0..8191
  const int sig0 = wid * 8;
  const float* Dp = D + 8 * lane;
  float lossacc = 0.f;

  #pragma unroll 1
  for (int g = 0; g < 2; ++g) {
    const int base = sig0 + g * 4;
    float sv[4];
    #pragma unroll
    for (int m = 0; m < 4; ++m) sv[m] = ST[(base + m) * 64 + lane];

    OmpState S0, S1, S2, S3;
    #pragma unroll
    for (int j = 0; j < 8; ++j) {
      S0.cr[j] = 0.f; S1.cr[j] = 0.f; S2.cr[j] = 0.f; S3.cr[j] = 0.f;
    }
    S0.omega = 0xFF; S1.omega = 0xFF; S2.omega = 0xFF; S3.omega = 0xFF;

    // init_corr for 4 signals directly into cr
    #pragma unroll 2
    for (int r = 0; r < 64; ++r) {
      const float4 d0 = *reinterpret_cast<const float4*>(Dp + r * KAT);
      const float4 d1 = *reinterpret_cast<const float4*>(Dp + r * KAT + 4);
      const float c0 = bcastf(sv[0], r);
      const float c1 = bcastf(sv[1], r);
      const float c2 = bcastf(sv[2], r);
      const float c3 = bcastf(sv[3], r);
      ICUPD(S0, c0) ICUPD(S1, c1) ICUPD(S2, c2) ICUPD(S3, c3)
    }

    RUN_PAIR(S0, S1, base + 0, base + 1, sv[0], sv[1])
    RUN_PAIR(S2, S3, base + 2, base + 3, sv[2], sv[3])
  }

  #pragma unroll
  for (int off = 32; off > 0; off >>= 1) lossacc += __shfl_xor(lossacc, off);
  if (lane == 0) atomicAdd(lossp, lossacc * (1.25f / 4194304.f));
}

extern "C" void kernel_launch(void* const* d_in, const int* in_sizes, int n_in,
                              void* d_out, int out_size, void* d_ws, size_t ws_size,
                              hipStream_t stream) {
  const float* ze = (const float*)d_in[0];
  const float* D  = (const float*)d_in[1];
  float* out0 = (float*)d_out;
  float* lossp = out0 + 4194304;
  float* coeffs = out0 + 4194305;

  float* wsf = (float*)d_ws;
  float* G  = wsf;              // 262144 floats
  float* DT = wsf + 262144;     // 32768 floats
  float* ST = wsf + 294912;     // 4194304 floats

  // zero loss + coeffs (out0 is fully overwritten)
  hipMemsetAsync((char*)d_out + 16777216ull, 0, 134217732ull, stream);

  hipLaunchKernelGGL(k_gram, dim3(1024), dim3(256), 0, stream, D, G, DT);
  hipLaunchKernelGGL(k_tr,   dim3(2048), dim3(256), 0, stream, ze, ST);
  hipLaunchKernelGGL(k_omp,  dim3(2048), dim3(256), 0, stream,
                     D, G, DT, ST, out0, lossp, coeffs);
}

// Round 6
// 266.925 us; speedup vs baseline: 2.9057x; 2.9057x over previous
//
#include <hip/hip_runtime.h>

#define NSIG  65536
#define KAT   512
#define CDIM  64

__device__ __forceinline__ float bcastf(float v, int l) {
  return __int_as_float(__builtin_amdgcn_readlane(__float_as_int(v), l));
}
__device__ __forceinline__ unsigned umaxu(unsigned a, unsigned b) {
  return a > b ? a : b;
}
__device__ __forceinline__ unsigned dppmax(unsigned v, const int ctrl) {
  switch (ctrl) {
    case 0xB1:  return umaxu(v, (unsigned)__builtin_amdgcn_mov_dpp((int)v, 0xB1, 0xF, 0xF, true));
    case 0x4E:  return umaxu(v, (unsigned)__builtin_amdgcn_mov_dpp((int)v, 0x4E, 0xF, 0xF, true));
    case 0x124: return umaxu(v, (unsigned)__builtin_amdgcn_mov_dpp((int)v, 0x124, 0xF, 0xF, true));
    default:    return umaxu(v, (unsigned)__builtin_amdgcn_mov_dpp((int)v, 0x128, 0xF, 0xF, true));
  }
}

// G = D^T D  [512][512]; DT[k][c] = D[c][k]
__global__ void k_gram(const float* __restrict__ D, float* __restrict__ G,
                       float* __restrict__ DT) {
  int tid = blockIdx.x * 256 + threadIdx.x;      // 262144 total
  int i = tid >> 9, j = tid & 511;
  float acc = 0.f;
  #pragma unroll 8
  for (int c = 0; c < CDIM; ++c) acc = fmaf(D[c * KAT + i], D[c * KAT + j], acc);
  G[tid] = acc;
  if (tid < KAT * CDIM) {
    int k = tid >> 6, c = tid & 63;
    DT[tid] = D[c * KAT + k];
  }
}

// ST[n][b] = z_e[b][n%64][n/2048][(n/64)%32]   (signal-major staging)
__global__ void k_tr(const float* __restrict__ ze, float* __restrict__ st) {
  __shared__ float tile[64][33];
  int cz = blockIdx.x >> 5;
  int h  = blockIdx.x & 31;
  int t  = threadIdx.x;
  #pragma unroll
  for (int q = 0; q < 8; ++q) {
    int idx = q * 256 + t;
    int b = idx >> 5, w = idx & 31;
    tile[b][w] = ze[b * 65536 + cz * 1024 + h * 32 + w];
  }
  __syncthreads();
  #pragma unroll
  for (int q = 0; q < 8; ++q) {
    int idx = q * 256 + t;
    int w = idx >> 6, b = idx & 63;
    st[(h * 2048 + w * 64 + cz) * 64 + b] = tile[b][w];
  }
}

__global__ __launch_bounds__(256) void k_omp(
    const float* __restrict__ D, const float* __restrict__ G,
    const float* __restrict__ DT, const float* __restrict__ ST,
    float* __restrict__ out0, float* __restrict__ lossp,
    float* __restrict__ coeffs) {
  const int lane = threadIdx.x & 63;
  const int wid  = (blockIdx.x * 256 + threadIdx.x) >> 6;   // 0..8191
  const int sig0 = wid * 8;

  // load 8 signals: lane r holds component r of each
  float s[8];
  #pragma unroll
  for (int m = 0; m < 8; ++m) s[m] = ST[(sig0 + m) * 64 + lane];

  // init_corr: lane holds atoms k = 8*lane + j; ic[m] doubles as the live
  // residual-correlation vector cr while signal m is processed (in-place).
  float ic[8][8];
  #pragma unroll
  for (int m = 0; m < 8; ++m)
    #pragma unroll
    for (int j = 0; j < 8; ++j) ic[m][j] = 0.f;

  const float* Dp = D + 8 * lane;
  #pragma unroll 4
  for (int r = 0; r < 64; ++r) {
    const float4 d0 = *reinterpret_cast<const float4*>(Dp + r * KAT);
    const float4 d1 = *reinterpret_cast<const float4*>(Dp + r * KAT + 4);
    #pragma unroll
    for (int m = 0; m < 8; ++m) {
      const float sc = bcastf(s[m], r);
      ic[m][0] = fmaf(d0.x, sc, ic[m][0]);
      ic[m][1] = fmaf(d0.y, sc, ic[m][1]);
      ic[m][2] = fmaf(d0.z, sc, ic[m][2]);
      ic[m][3] = fmaf(d0.w, sc, ic[m][3]);
      ic[m][4] = fmaf(d1.x, sc, ic[m][4]);
      ic[m][5] = fmaf(d1.y, sc, ic[m][5]);
      ic[m][6] = fmaf(d1.z, sc, ic[m][6]);
      ic[m][7] = fmaf(d1.w, sc, ic[m][7]);
    }
  }

  float lossacc = 0.f;

  #pragma unroll
  for (int m = 0; m < 8; ++m) {
    const int n = sig0 + m;
    int omega = 0xFF;
    int I0 = 0, I1 = 0, I2 = 0, I3 = 0, I4 = 0;
    // L off-diagonals (L_t,u = w_u at iteration t) + inverse diagonals d*.
    float L10 = 0, L20 = 0, L21 = 0;
    float L30 = 0, L31 = 0, L32 = 0;
    float L40 = 0, L41 = 0, L42 = 0, L43 = 0;
    float d1v = 1.f, d2v = 1.f, d3v = 1.f, d4v = 1.f;
    float y0v = 0, y1v = 0, y2v = 0, y3v = 0, y4v = 0;
    // orthogonalized columns Q_t = L^-1-transformed G rows (this lane's 8 cols)
    float Q0[8], Q1[8], Q2[8], Q3[8];

    #pragma unroll 1
    for (int it = 0; it < 5; ++it) {
      // ---- argmax of |cr| * omega: DPP, first-index tie-break ----
      unsigned ab[8];
      #pragma unroll
      for (int j = 0; j < 8; ++j) {
        unsigned a = __float_as_uint(ic[m][j]) & 0x7FFFFFFFu;
        ab[j] = ((omega >> j) & 1) ? a : 0u;
      }
      unsigned la = umaxu(umaxu(umaxu(ab[0], ab[1]), umaxu(ab[2], ab[3])),
                          umaxu(umaxu(ab[4], ab[5]), umaxu(ab[6], ab[7])));
      unsigned rmax = la;
      rmax = dppmax(rmax, 0xB1);
      rmax = dppmax(rmax, 0x4E);
      rmax = dppmax(rmax, 0x124);
      rmax = dppmax(rmax, 0x128);
      unsigned gmu = umaxu(
          umaxu((unsigned)__builtin_amdgcn_readlane((int)rmax, 0),
                (unsigned)__builtin_amdgcn_readlane((int)rmax, 16)),
          umaxu((unsigned)__builtin_amdgcn_readlane((int)rmax, 32),
                (unsigned)__builtin_amdgcn_readlane((int)rmax, 48)));
      unsigned long long ball = __ballot(la == gmu);
      const int sl = __ffsll((long long)ball) - 1;     // lowest winning lane
      int jb = 7;
      jb = (ab[6] == gmu) ? 6 : jb;
      jb = (ab[5] == gmu) ? 5 : jb;
      jb = (ab[4] == gmu) ? 4 : jb;
      jb = (ab[3] == gmu) ? 3 : jb;
      jb = (ab[2] == gmu) ? 2 : jb;
      jb = (ab[1] == gmu) ? 1 : jb;
      jb = (ab[0] == gmu) ? 0 : jb;
      const int jj = __builtin_amdgcn_readlane(jb, sl) & 7;
      const int khat = (sl << 3) | jj;
      if (lane == sl) omega &= ~(1 << jj);

      // issue the new G row load immediately (used after the scalar chain)
      float4 na = {0, 0, 0, 0}, nbv = {0, 0, 0, 0};
      if (it < 4) {
        na  = *reinterpret_cast<const float4*>(G + khat * KAT + 8 * lane);
        nbv = *reinterpret_cast<const float4*>(G + khat * KAT + 8 * lane + 4);
      }

      // ---- extract w_u = Q_u[khat], crv = cr[khat] ----
      float w0 = 0.f, w1 = 0.f, w2 = 0.f, w3 = 0.f;
      if (it > 0) {
        float e = Q0[0];
        e = (jj == 1) ? Q0[1] : e; e = (jj == 2) ? Q0[2] : e;
        e = (jj == 3) ? Q0[3] : e; e = (jj == 4) ? Q0[4] : e;
        e = (jj == 5) ? Q0[5] : e; e = (jj == 6) ? Q0[6] : e;
        e = (jj == 7) ? Q0[7] : e;
        w0 = bcastf(e, sl);
      }
      if (it > 1) {
        float e = Q1[0];
        e = (jj == 1) ? Q1[1] : e; e = (jj == 2) ? Q1[2] : e;
        e = (jj == 3) ? Q1[3] : e; e = (jj == 4) ? Q1[4] : e;
        e = (jj == 5) ? Q1[5] : e; e = (jj == 6) ? Q1[6] : e;
        e = (jj == 7) ? Q1[7] : e;
        w1 = bcastf(e, sl);
      }
      if (it > 2) {
        float e = Q2[0];
        e = (jj == 1) ? Q2[1] : e; e = (jj == 2) ? Q2[2] : e;
        e = (jj == 3) ? Q2[3] : e; e = (jj == 4) ? Q2[4] : e;
        e = (jj == 5) ? Q2[5] : e; e = (jj == 6) ? Q2[6] : e;
        e = (jj == 7) ? Q2[7] : e;
        w2 = bcastf(e, sl);
      }
      if (it > 3) {
        float e = Q3[0];
        e = (jj == 1) ? Q3[1] : e; e = (jj == 2) ? Q3[2] : e;
        e = (jj == 3) ? Q3[3] : e; e = (jj == 4) ? Q3[4] : e;
        e = (jj == 5) ? Q3[5] : e; e = (jj == 6) ? Q3[6] : e;
        e = (jj == 7) ? Q3[7] : e;
        w3 = bcastf(e, sl);
      }
      float crv;
      {
        float e = ic[m][0];
        e = (jj == 1) ? ic[m][1] : e; e = (jj == 2) ? ic[m][2] : e;
        e = (jj == 3) ? ic[m][3] : e; e = (jj == 4) ? ic[m][4] : e;
        e = (jj == 5) ? ic[m][5] : e; e = (jj == 6) ? ic[m][6] : e;
        e = (jj == 7) ? ic[m][7] : e;
        crv = bcastf(e, sl);
      }

      // ---- scalar chain: dn = 1/sqrt(1-||w||^2); y_it = crv * dn ----
      float s2 = 1.f - w0 * w0 - w1 * w1 - w2 * w2 - w3 * w3;
      float dn = (it == 0) ? 1.f : __builtin_amdgcn_rsqf(s2);
      float yn = crv * dn;
      if (it == 0) { I0 = khat; y0v = yn; }
      if (it == 1) { I1 = khat; y1v = yn; L10 = w0; d1v = dn; }
      if (it == 2) { I2 = khat; y2v = yn; L20 = w0; L21 = w1; d2v = dn; }
      if (it == 3) { I3 = khat; y3v = yn; L30 = w0; L31 = w1; L32 = w2; d3v = dn; }
      if (it == 4) { I4 = khat; y4v = yn; L40 = w0; L41 = w1; L42 = w2; L43 = w3; d4v = dn; }

      // ---- orthogonalize new column; rank-1 residual update ----
      if (it < 4) {
        float qn[8];
        qn[0] = na.x;  qn[1] = na.y;  qn[2] = na.z;  qn[3] = na.w;
        qn[4] = nbv.x; qn[5] = nbv.y; qn[6] = nbv.z; qn[7] = nbv.w;
        #pragma unroll
        for (int j = 0; j < 8; ++j) {
          float q = qn[j];
          if (it > 0) q = fmaf(-w0, Q0[j], q);
          if (it > 1) q = fmaf(-w1, Q1[j], q);
          if (it > 2) q = fmaf(-w2, Q2[j], q);
          qn[j] = q * dn;
        }
        if (it == 0) {
          for (int j = 0; j < 8; ++j) Q0[j] = qn[j];
        }
        if (it == 1) {
          for (int j = 0; j < 8; ++j) Q1[j] = qn[j];
        }
        if (it == 2) {
          for (int j = 0; j < 8; ++j) Q2[j] = qn[j];
        }
        if (it == 3) {
          for (int j = 0; j < 8; ++j) Q3[j] = qn[j];
        }
        #pragma unroll
        for (int j = 0; j < 8; ++j) ic[m][j] = fmaf(-yn, qn[j], ic[m][j]);
      }
    } // it

    // ---- back-substitution (once) + epilogue ----
    float x4 = y4v * d4v;
    float x3 = (y3v - L43 * x4) * d3v;
    float x2 = (y2v - L32 * x3 - L42 * x4) * d2v;
    float x1 = (y1v - L21 * x2 - L31 * x3 - L41 * x4) * d1v;
    float x0 =  y0v - L10 * x1 - L20 * x2 - L30 * x3 - L40 * x4;

    if (lane < 5) {
      int It = I0; float xt = x0;
      if (lane == 1) { It = I1; xt = x1; }
      if (lane == 2) { It = I2; xt = x2; }
      if (lane == 3) { It = I3; xt = x3; }
      if (lane == 4) { It = I4; xt = x4; }
      coeffs[(long)It * NSIG + n] = xt;
    }
    float rec = x0 * DT[I0 * 64 + lane];
    rec = fmaf(x1, DT[I1 * 64 + lane], rec);
    rec = fmaf(x2, DT[I2 * 64 + lane], rec);
    rec = fmaf(x3, DT[I3 * 64 + lane], rec);
    rec = fmaf(x4, DT[I4 * 64 + lane], rec);
    const float zv = s[m];
    const float d = rec - zv;
    lossacc = fmaf(d, d, lossacc);
    const int offn = (n & 63) * 1024 + (n >> 11) * 32 + ((n >> 6) & 31);
    out0[lane * 65536 + offn] = zv + d;   // z + (z_dl - z), faithful
  } // m

  #pragma unroll
  for (int off = 32; off > 0; off >>= 1) lossacc += __shfl_xor(lossacc, off);
  if (lane == 0) atomicAdd(lossp, lossacc * (1.25f / 4194304.f));
}

extern "C" void kernel_launch(void* const* d_in, const int* in_sizes, int n_in,
                              void* d_out, int out_size, void* d_ws, size_t ws_size,
                              hipStream_t stream) {
  const float* ze = (const float*)d_in[0];
  const float* D  = (const float*)d_in[1];
  float* out0 = (float*)d_out;
  float* lossp = out0 + 4194304;
  float* coeffs = out0 + 4194305;

  float* wsf = (float*)d_ws;
  float* G  = wsf;              // 262144 floats
  float* DT = wsf + 262144;     // 32768 floats
  float* ST = wsf + 294912;     // 4194304 floats

  // zero loss + coeffs (out0 is fully overwritten)
  (void)hipMemsetAsync((char*)d_out + 16777216ull, 0, 134217732ull, stream);

  hipLaunchKernelGGL(k_gram, dim3(1024), dim3(256), 0, stream, D, G, DT);
  hipLaunchKernelGGL(k_tr,   dim3(2048), dim3(256), 0, stream, ze, ST);
  hipLaunchKernelGGL(k_omp,  dim3(2048), dim3(256), 0, stream,
                     D, G, DT, ST, out0, lossp, coeffs);
}

// Round 7
// 251.928 us; speedup vs baseline: 3.0787x; 1.0595x over previous
//
#include <hip/hip_runtime.h>

#define NSIG  65536
#define KAT   512
#define CDIM  64

__device__ __forceinline__ float bcastf(float v, int l) {
  return __int_as_float(__builtin_amdgcn_readlane(__float_as_int(v), l));
}
__device__ __forceinline__ unsigned umaxu(unsigned a, unsigned b) {
  return a > b ? a : b;
}
__device__ __forceinline__ unsigned dppmax(unsigned v, const int ctrl) {
  switch (ctrl) {
    case 0xB1:  return umaxu(v, (unsigned)__builtin_amdgcn_mov_dpp((int)v, 0xB1, 0xF, 0xF, true));
    case 0x4E:  return umaxu(v, (unsigned)__builtin_amdgcn_mov_dpp((int)v, 0x4E, 0xF, 0xF, true));
    case 0x124: return umaxu(v, (unsigned)__builtin_amdgcn_mov_dpp((int)v, 0x124, 0xF, 0xF, true));
    default:    return umaxu(v, (unsigned)__builtin_amdgcn_mov_dpp((int)v, 0x128, 0xF, 0xF, true));
  }
}

// G = D^T D  [512][512]; DT[k][c] = D[c][k]
__global__ void k_gram(const float* __restrict__ D, float* __restrict__ G,
                       float* __restrict__ DT) {
  int tid = blockIdx.x * 256 + threadIdx.x;      // 262144 total
  int i = tid >> 9, j = tid & 511;
  float acc = 0.f;
  #pragma unroll 8
  for (int c = 0; c < CDIM; ++c) acc = fmaf(D[c * KAT + i], D[c * KAT + j], acc);
  G[tid] = acc;
  if (tid < KAT * CDIM) {
    int k = tid >> 6, c = tid & 63;
    DT[tid] = D[c * KAT + k];
  }
}

// ST[n][b] = z_e[b][n%64][n/2048][(n/64)%32]   (signal-major staging)
__global__ void k_tr(const float* __restrict__ ze, float* __restrict__ st) {
  __shared__ float tile[64][33];
  int cz = blockIdx.x >> 5;
  int h  = blockIdx.x & 31;
  int t  = threadIdx.x;
  #pragma unroll
  for (int q = 0; q < 8; ++q) {
    int idx = q * 256 + t;
    int b = idx >> 5, w = idx & 31;
    tile[b][w] = ze[b * 65536 + cz * 1024 + h * 32 + w];
  }
  __syncthreads();
  #pragma unroll
  for (int q = 0; q < 8; ++q) {
    int idx = q * 256 + t;
    int w = idx >> 6, b = idx & 63;
    st[(h * 2048 + w * 64 + cz) * 64 + b] = tile[b][w];
  }
}

// One full OMP solve for one signal. cr = residual correlations (in regs),
// modified in place. Returns squared reconstruction error contribution.
__device__ __forceinline__ float omp_one(float (&cr)[8], const float* __restrict__ G,
                                         const float* __restrict__ DT,
                                         float* __restrict__ out0,
                                         float* __restrict__ coeffs,
                                         int n, int lane, float zv) {
  int omega = 0xFF;
  int I0 = 0, I1 = 0, I2 = 0, I3 = 0, I4 = 0;
  float L10 = 0, L20 = 0, L21 = 0;
  float L30 = 0, L31 = 0, L32 = 0;
  float L40 = 0, L41 = 0, L42 = 0, L43 = 0;
  float d1v = 1.f, d2v = 1.f, d3v = 1.f, d4v = 1.f;
  float y0v = 0, y1v = 0, y2v = 0, y3v = 0, y4v = 0;
  float Q0[8], Q1[8], Q2[8], Q3[8];

  #pragma unroll 1
  for (int it = 0; it < 5; ++it) {
    // ---- argmax of |cr| * omega: DPP, first-index tie-break ----
    unsigned ab[8];
    #pragma unroll
    for (int j = 0; j < 8; ++j) {
      unsigned a = __float_as_uint(cr[j]) & 0x7FFFFFFFu;
      ab[j] = ((omega >> j) & 1) ? a : 0u;
    }
    unsigned la = umaxu(umaxu(umaxu(ab[0], ab[1]), umaxu(ab[2], ab[3])),
                        umaxu(umaxu(ab[4], ab[5]), umaxu(ab[6], ab[7])));
    unsigned rmax = la;
    rmax = dppmax(rmax, 0xB1);
    rmax = dppmax(rmax, 0x4E);
    rmax = dppmax(rmax, 0x124);
    rmax = dppmax(rmax, 0x128);
    unsigned gmu = umaxu(
        umaxu((unsigned)__builtin_amdgcn_readlane((int)rmax, 0),
              (unsigned)__builtin_amdgcn_readlane((int)rmax, 16)),
        umaxu((unsigned)__builtin_amdgcn_readlane((int)rmax, 32),
              (unsigned)__builtin_amdgcn_readlane((int)rmax, 48)));
    unsigned long long ball = __ballot(la == gmu);
    const int sl = __ffsll((long long)ball) - 1;     // lowest winning lane
    int jb = 7;
    jb = (ab[6] == gmu) ? 6 : jb;
    jb = (ab[5] == gmu) ? 5 : jb;
    jb = (ab[4] == gmu) ? 4 : jb;
    jb = (ab[3] == gmu) ? 3 : jb;
    jb = (ab[2] == gmu) ? 2 : jb;
    jb = (ab[1] == gmu) ? 1 : jb;
    jb = (ab[0] == gmu) ? 0 : jb;
    const int jj = __builtin_amdgcn_readlane(jb, sl) & 7;
    const int khat = (sl << 3) | jj;
    if (lane == sl) omega &= ~(1 << jj);

    // issue the new G row load immediately (used after the scalar chain)
    float4 na = {0, 0, 0, 0}, nbv = {0, 0, 0, 0};
    if (it < 4) {
      na  = *reinterpret_cast<const float4*>(G + khat * KAT + 8 * lane);
      nbv = *reinterpret_cast<const float4*>(G + khat * KAT + 8 * lane + 4);
    }

    // ---- extract w_u = Q_u[khat], crv = cr[khat] ----
    float w0 = 0.f, w1 = 0.f, w2 = 0.f, w3 = 0.f;
    if (it > 0) {
      float e = Q0[0];
      e = (jj == 1) ? Q0[1] : e; e = (jj == 2) ? Q0[2] : e;
      e = (jj == 3) ? Q0[3] : e; e = (jj == 4) ? Q0[4] : e;
      e = (jj == 5) ? Q0[5] : e; e = (jj == 6) ? Q0[6] : e;
      e = (jj == 7) ? Q0[7] : e;
      w0 = bcastf(e, sl);
    }
    if (it > 1) {
      float e = Q1[0];
      e = (jj == 1) ? Q1[1] : e; e = (jj == 2) ? Q1[2] : e;
      e = (jj == 3) ? Q1[3] : e; e = (jj == 4) ? Q1[4] : e;
      e = (jj == 5) ? Q1[5] : e; e = (jj == 6) ? Q1[6] : e;
      e = (jj == 7) ? Q1[7] : e;
      w1 = bcastf(e, sl);
    }
    if (it > 2) {
      float e = Q2[0];
      e = (jj == 1) ? Q2[1] : e; e = (jj == 2) ? Q2[2] : e;
      e = (jj == 3) ? Q2[3] : e; e = (jj == 4) ? Q2[4] : e;
      e = (jj == 5) ? Q2[5] : e; e = (jj == 6) ? Q2[6] : e;
      e = (jj == 7) ? Q2[7] : e;
      w2 = bcastf(e, sl);
    }
    if (it > 3) {
      float e = Q3[0];
      e = (jj == 1) ? Q3[1] : e; e = (jj == 2) ? Q3[2] : e;
      e = (jj == 3) ? Q3[3] : e; e = (jj == 4) ? Q3[4] : e;
      e = (jj == 5) ? Q3[5] : e; e = (jj == 6) ? Q3[6] : e;
      e = (jj == 7) ? Q3[7] : e;
      w3 = bcastf(e, sl);
    }
    float crv;
    {
      float e = cr[0];
      e = (jj == 1) ? cr[1] : e; e = (jj == 2) ? cr[2] : e;
      e = (jj == 3) ? cr[3] : e; e = (jj == 4) ? cr[4] : e;
      e = (jj == 5) ? cr[5] : e; e = (jj == 6) ? cr[6] : e;
      e = (jj == 7) ? cr[7] : e;
      crv = bcastf(e, sl);
    }

    // ---- scalar chain: dn = 1/sqrt(1-||w||^2); y_it = crv * dn ----
    float s2 = 1.f - w0 * w0 - w1 * w1 - w2 * w2 - w3 * w3;
    float dn = (it == 0) ? 1.f : __builtin_amdgcn_rsqf(s2);
    float yn = crv * dn;
    if (it == 0) { I0 = khat; y0v = yn; }
    if (it == 1) { I1 = khat; y1v = yn; L10 = w0; d1v = dn; }
    if (it == 2) { I2 = khat; y2v = yn; L20 = w0; L21 = w1; d2v = dn; }
    if (it == 3) { I3 = khat; y3v = yn; L30 = w0; L31 = w1; L32 = w2; d3v = dn; }
    if (it == 4) { I4 = khat; y4v = yn; L40 = w0; L41 = w1; L42 = w2; L43 = w3; d4v = dn; }

    // ---- orthogonalize new column; rank-1 residual update ----
    if (it < 4) {
      float qn[8];
      qn[0] = na.x;  qn[1] = na.y;  qn[2] = na.z;  qn[3] = na.w;
      qn[4] = nbv.x; qn[5] = nbv.y; qn[6] = nbv.z; qn[7] = nbv.w;
      #pragma unroll
      for (int j = 0; j < 8; ++j) {
        float q = qn[j];
        if (it > 0) q = fmaf(-w0, Q0[j], q);
        if (it > 1) q = fmaf(-w1, Q1[j], q);
        if (it > 2) q = fmaf(-w2, Q2[j], q);
        qn[j] = q * dn;
      }
      if (it == 0) {
        for (int j = 0; j < 8; ++j) Q0[j] = qn[j];
      }
      if (it == 1) {
        for (int j = 0; j < 8; ++j) Q1[j] = qn[j];
      }
      if (it == 2) {
        for (int j = 0; j < 8; ++j) Q2[j] = qn[j];
      }
      if (it == 3) {
        for (int j = 0; j < 8; ++j) Q3[j] = qn[j];
      }
      #pragma unroll
      for (int j = 0; j < 8; ++j) cr[j] = fmaf(-yn, qn[j], cr[j]);
    }
  } // it

  // ---- back-substitution (once) + epilogue ----
  float x4 = y4v * d4v;
  float x3 = (y3v - L43 * x4) * d3v;
  float x2 = (y2v - L32 * x3 - L42 * x4) * d2v;
  float x1 = (y1v - L21 * x2 - L31 * x3 - L41 * x4) * d1v;
  float x0 =  y0v - L10 * x1 - L20 * x2 - L30 * x3 - L40 * x4;

  if (lane < 5) {
    int It = I0; float xt = x0;
    if (lane == 1) { It = I1; xt = x1; }
    if (lane == 2) { It = I2; xt = x2; }
    if (lane == 3) { It = I3; xt = x3; }
    if (lane == 4) { It = I4; xt = x4; }
    coeffs[(long)It * NSIG + n] = xt;
  }
  float rec = x0 * DT[I0 * 64 + lane];
  rec = fmaf(x1, DT[I1 * 64 + lane], rec);
  rec = fmaf(x2, DT[I2 * 64 + lane], rec);
  rec = fmaf(x3, DT[I3 * 64 + lane], rec);
  rec = fmaf(x4, DT[I4 * 64 + lane], rec);
  const float d = rec - zv;
  const int offn = (n & 63) * 1024 + (n >> 11) * 32 + ((n >> 6) & 31);
  out0[lane * 65536 + offn] = zv + d;    // z + (z_dl - z), faithful
  return d * d;
}

__global__ __launch_bounds__(256) void k_omp(
    const float* __restrict__ D, const float* __restrict__ G,
    const float* __restrict__ DT, const float* __restrict__ ST,
    float* __restrict__ out0, float* __restrict__ lossp,
    float* __restrict__ coeffs) {
  const int lane = threadIdx.x & 63;
  const int wid  = (blockIdx.x * 256 + threadIdx.x) >> 6;   // 0..8191
  const int sig0 = wid * 8;
  const float* Dp = D + 8 * lane;
  float lossacc = 0.f;

  // 2 batches of 4 signals: keeps peak live-register count ~96 (cr 32 + Q 32)
  // so nothing spills to scratch. D is streamed from L2 twice (2.1 GB, OK).
  #pragma unroll 1
  for (int g = 0; g < 2; ++g) {
    const int base = sig0 + g * 4;
    float sv0 = ST[(base + 0) * 64 + lane];
    float sv1 = ST[(base + 1) * 64 + lane];
    float sv2 = ST[(base + 2) * 64 + lane];
    float sv3 = ST[(base + 3) * 64 + lane];

    float cr0[8], cr1[8], cr2[8], cr3[8];
    #pragma unroll
    for (int j = 0; j < 8; ++j) { cr0[j] = 0.f; cr1[j] = 0.f; cr2[j] = 0.f; cr3[j] = 0.f; }

    #pragma unroll 2
    for (int r = 0; r < 64; ++r) {
      const float4 d0 = *reinterpret_cast<const float4*>(Dp + r * KAT);
      const float4 d1 = *reinterpret_cast<const float4*>(Dp + r * KAT + 4);
      const float c0 = bcastf(sv0, r);
      const float c1 = bcastf(sv1, r);
      const float c2 = bcastf(sv2, r);
      const float c3 = bcastf(sv3, r);
      cr0[0] = fmaf(d0.x, c0, cr0[0]); cr0[1] = fmaf(d0.y, c0, cr0[1]);
      cr0[2] = fmaf(d0.z, c0, cr0[2]); cr0[3] = fmaf(d0.w, c0, cr0[3]);
      cr0[4] = fmaf(d1.x, c0, cr0[4]); cr0[5] = fmaf(d1.y, c0, cr0[5]);
      cr0[6] = fmaf(d1.z, c0, cr0[6]); cr0[7] = fmaf(d1.w, c0, cr0[7]);
      cr1[0] = fmaf(d0.x, c1, cr1[0]); cr1[1] = fmaf(d0.y, c1, cr1[1]);
      cr1[2] = fmaf(d0.z, c1, cr1[2]); cr1[3] = fmaf(d0.w, c1, cr1[3]);
      cr1[4] = fmaf(d1.x, c1, cr1[4]); cr1[5] = fmaf(d1.y, c1, cr1[5]);
      cr1[6] = fmaf(d1.z, c1, cr1[6]); cr1[7] = fmaf(d1.w, c1, cr1[7]);
      cr2[0] = fmaf(d0.x, c2, cr2[0]); cr2[1] = fmaf(d0.y, c2, cr2[1]);
      cr2[2] = fmaf(d0.z, c2, cr2[2]); cr2[3] = fmaf(d0.w, c2, cr2[3]);
      cr2[4] = fmaf(d1.x, c2, cr2[4]); cr2[5] = fmaf(d1.y, c2, cr2[5]);
      cr2[6] = fmaf(d1.z, c2, cr2[6]); cr2[7] = fmaf(d1.w, c2, cr2[7]);
      cr3[0] = fmaf(d0.x, c3, cr3[0]); cr3[1] = fmaf(d0.y, c3, cr3[1]);
      cr3[2] = fmaf(d0.z, c3, cr3[2]); cr3[3] = fmaf(d0.w, c3, cr3[3]);
      cr3[4] = fmaf(d1.x, c3, cr3[4]); cr3[5] = fmaf(d1.y, c3, cr3[5]);
      cr3[6] = fmaf(d1.z, c3, cr3[6]); cr3[7] = fmaf(d1.w, c3, cr3[7]);
    }

    lossacc += omp_one(cr0, G, DT, out0, coeffs, base + 0, lane, sv0);
    lossacc += omp_one(cr1, G, DT, out0, coeffs, base + 1, lane, sv1);
    lossacc += omp_one(cr2, G, DT, out0, coeffs, base + 2, lane, sv2);
    lossacc += omp_one(cr3, G, DT, out0, coeffs, base + 3, lane, sv3);
  }

  #pragma unroll
  for (int off = 32; off > 0; off >>= 1) lossacc += __shfl_xor(lossacc, off);
  if (lane == 0) atomicAdd(lossp, lossacc * (1.25f / 4194304.f));
}

extern "C" void kernel_launch(void* const* d_in, const int* in_sizes, int n_in,
                              void* d_out, int out_size, void* d_ws, size_t ws_size,
                              hipStream_t stream) {
  const float* ze = (const float*)d_in[0];
  const float* D  = (const float*)d_in[1];
  float* out0 = (float*)d_out;
  float* lossp = out0 + 4194304;
  float* coeffs = out0 + 4194305;

  float* wsf = (float*)d_ws;
  float* G  = wsf;              // 262144 floats
  float* DT = wsf + 262144;     // 32768 floats
  float* ST = wsf + 294912;     // 4194304 floats

  // zero loss + coeffs (out0 is fully overwritten)
  (void)hipMemsetAsync((char*)d_out + 16777216ull, 0, 134217732ull, stream);

  hipLaunchKernelGGL(k_gram, dim3(1024), dim3(256), 0, stream, D, G, DT);
  hipLaunchKernelGGL(k_tr,   dim3(2048), dim3(256), 0, stream, ze, ST);
  hipLaunchKernelGGL(k_omp,  dim3(2048), dim3(256), 0, stream,
                     D, G, DT, ST, out0, lossp, coeffs);
}

// Round 8
// 221.741 us; speedup vs baseline: 3.4978x; 1.1361x over previous
//
#include <hip/hip_runtime.h>

#define NSIG  65536
#define KAT   512
#define CDIM  64

__device__ __forceinline__ float bcastf(float v, int l) {
  return __int_as_float(__builtin_amdgcn_readlane(__float_as_int(v), l));
}
__device__ __forceinline__ unsigned umaxu(unsigned a, unsigned b) {
  return a > b ? a : b;
}
__device__ __forceinline__ unsigned dppmax(unsigned v, const int ctrl) {
  switch (ctrl) {
    case 0xB1:  return umaxu(v, (unsigned)__builtin_amdgcn_mov_dpp((int)v, 0xB1, 0xF, 0xF, true));
    case 0x4E:  return umaxu(v, (unsigned)__builtin_amdgcn_mov_dpp((int)v, 0x4E, 0xF, 0xF, true));
    case 0x124: return umaxu(v, (unsigned)__builtin_amdgcn_mov_dpp((int)v, 0x124, 0xF, 0xF, true));
    default:    return umaxu(v, (unsigned)__builtin_amdgcn_mov_dpp((int)v, 0x128, 0xF, 0xF, true));
  }
}

// G = D^T D  [512][512]; DT[k][c] = D[c][k]
__global__ void k_gram(const float* __restrict__ D, float* __restrict__ G,
                       float* __restrict__ DT) {
  int tid = blockIdx.x * 256 + threadIdx.x;      // 262144 total
  int i = tid >> 9, j = tid & 511;
  float acc = 0.f;
  #pragma unroll 8
  for (int c = 0; c < CDIM; ++c) acc = fmaf(D[c * KAT + i], D[c * KAT + j], acc);
  G[tid] = acc;
  if (tid < KAT * CDIM) {
    int k = tid >> 6, c = tid & 63;
    DT[tid] = D[c * KAT + k];
  }
}

// ST[n][b] = z_e[b][n%64][n/2048][(n/64)%32]   (signal-major staging)
__global__ void k_tr(const float* __restrict__ ze, float* __restrict__ st) {
  __shared__ float tile[64][33];
  int cz = blockIdx.x >> 5;
  int h  = blockIdx.x & 31;
  int t  = threadIdx.x;
  #pragma unroll
  for (int q = 0; q < 8; ++q) {
    int idx = q * 256 + t;
    int b = idx >> 5, w = idx & 31;
    tile[b][w] = ze[b * 65536 + cz * 1024 + h * 32 + w];
  }
  __syncthreads();
  #pragma unroll
  for (int q = 0; q < 8; ++q) {
    int idx = q * 256 + t;
    int w = idx >> 6, b = idx & 63;
    st[(h * 2048 + w * 64 + cz) * 64 + b] = tile[b][w];
  }
}

// ---- all-scalar helpers (no local arrays anywhere: forces registers) ----
#define DECL8Z(p) float p##0=0.f,p##1=0.f,p##2=0.f,p##3=0.f,p##4=0.f,p##5=0.f,p##6=0.f,p##7=0.f
#define FMA8(p, sc)                                         \
  p##0 = fmaf(d0.x, sc, p##0); p##1 = fmaf(d0.y, sc, p##1); \
  p##2 = fmaf(d0.z, sc, p##2); p##3 = fmaf(d0.w, sc, p##3); \
  p##4 = fmaf(d1.x, sc, p##4); p##5 = fmaf(d1.y, sc, p##5); \
  p##6 = fmaf(d1.z, sc, p##6); p##7 = fmaf(d1.w, sc, p##7)
#define SEL8(e, p)                                          \
  e = p##0;                                                 \
  e = (jj == 1) ? p##1 : e; e = (jj == 2) ? p##2 : e;       \
  e = (jj == 3) ? p##3 : e; e = (jj == 4) ? p##4 : e;       \
  e = (jj == 5) ? p##5 : e; e = (jj == 6) ? p##6 : e;       \
  e = (jj == 7) ? p##7 : e
#define ORTHO8(Qp, w)                                       \
  qn0 = fmaf(-(w), Qp##0, qn0); qn1 = fmaf(-(w), Qp##1, qn1); \
  qn2 = fmaf(-(w), Qp##2, qn2); qn3 = fmaf(-(w), Qp##3, qn3); \
  qn4 = fmaf(-(w), Qp##4, qn4); qn5 = fmaf(-(w), Qp##5, qn5); \
  qn6 = fmaf(-(w), Qp##6, qn6); qn7 = fmaf(-(w), Qp##7, qn7)
#define SETQ8(Qp)                                           \
  Qp##0 = qn0; Qp##1 = qn1; Qp##2 = qn2; Qp##3 = qn3;       \
  Qp##4 = qn4; Qp##5 = qn5; Qp##6 = qn6; Qp##7 = qn7

// One full OMP solve for one signal; cr held in 8 scalar refs.
__device__ __forceinline__ float omp_one(
    float& c0, float& c1, float& c2, float& c3,
    float& c4, float& c5, float& c6, float& c7,
    const float* __restrict__ G, const float* __restrict__ DT,
    float* __restrict__ out0, float* __restrict__ coeffs,
    int n, int lane, float zv) {
  int omega = 0xFF;
  int I0 = 0, I1 = 0, I2 = 0, I3 = 0, I4 = 0;
  float L10 = 0, L20 = 0, L21 = 0;
  float L30 = 0, L31 = 0, L32 = 0;
  float L40 = 0, L41 = 0, L42 = 0, L43 = 0;
  float d1v = 1.f, d2v = 1.f, d3v = 1.f, d4v = 1.f;
  float y0v = 0, y1v = 0, y2v = 0, y3v = 0, y4v = 0;
  DECL8Z(Qa); DECL8Z(Qb); DECL8Z(Qc); DECL8Z(Qd);

  #pragma unroll 1
  for (int it = 0; it < 5; ++it) {
    // ---- argmax of |cr|*omega: DPP reduce, first-index tie-break ----
    unsigned ab0 = (omega & 1)        ? (__float_as_uint(c0) & 0x7FFFFFFFu) : 0u;
    unsigned ab1 = ((omega >> 1) & 1) ? (__float_as_uint(c1) & 0x7FFFFFFFu) : 0u;
    unsigned ab2 = ((omega >> 2) & 1) ? (__float_as_uint(c2) & 0x7FFFFFFFu) : 0u;
    unsigned ab3 = ((omega >> 3) & 1) ? (__float_as_uint(c3) & 0x7FFFFFFFu) : 0u;
    unsigned ab4 = ((omega >> 4) & 1) ? (__float_as_uint(c4) & 0x7FFFFFFFu) : 0u;
    unsigned ab5 = ((omega >> 5) & 1) ? (__float_as_uint(c5) & 0x7FFFFFFFu) : 0u;
    unsigned ab6 = ((omega >> 6) & 1) ? (__float_as_uint(c6) & 0x7FFFFFFFu) : 0u;
    unsigned ab7 = ((omega >> 7) & 1) ? (__float_as_uint(c7) & 0x7FFFFFFFu) : 0u;
    unsigned la = umaxu(umaxu(umaxu(ab0, ab1), umaxu(ab2, ab3)),
                        umaxu(umaxu(ab4, ab5), umaxu(ab6, ab7)));
    unsigned rmax = la;
    rmax = dppmax(rmax, 0xB1);
    rmax = dppmax(rmax, 0x4E);
    rmax = dppmax(rmax, 0x124);
    rmax = dppmax(rmax, 0x128);
    unsigned gmu = umaxu(
        umaxu((unsigned)__builtin_amdgcn_readlane((int)rmax, 0),
              (unsigned)__builtin_amdgcn_readlane((int)rmax, 16)),
        umaxu((unsigned)__builtin_amdgcn_readlane((int)rmax, 32),
              (unsigned)__builtin_amdgcn_readlane((int)rmax, 48)));
    unsigned long long ball = __ballot(la == gmu);
    const int sl = __ffsll((long long)ball) - 1;   // lowest winning lane
    int jb = 7;
    jb = (ab6 == gmu) ? 6 : jb;
    jb = (ab5 == gmu) ? 5 : jb;
    jb = (ab4 == gmu) ? 4 : jb;
    jb = (ab3 == gmu) ? 3 : jb;
    jb = (ab2 == gmu) ? 2 : jb;
    jb = (ab1 == gmu) ? 1 : jb;
    jb = (ab0 == gmu) ? 0 : jb;
    const int jj = __builtin_amdgcn_readlane(jb, sl) & 7;
    const int khat = (sl << 3) | jj;
    if (lane == sl) omega &= ~(1 << jj);

    // issue the new G row load immediately (consumed after scalar chain)
    float4 na = {0, 0, 0, 0}, nbv = {0, 0, 0, 0};
    if (it < 4) {
      na  = *reinterpret_cast<const float4*>(G + khat * KAT + 8 * lane);
      nbv = *reinterpret_cast<const float4*>(G + khat * KAT + 8 * lane + 4);
    }

    // ---- extract w_u = Q_u[khat], crv = cr[khat] ----
    float w0 = 0.f, w1 = 0.f, w2 = 0.f, w3 = 0.f;
    if (it > 0) { float e; SEL8(e, Qa); w0 = bcastf(e, sl); }
    if (it > 1) { float e; SEL8(e, Qb); w1 = bcastf(e, sl); }
    if (it > 2) { float e; SEL8(e, Qc); w2 = bcastf(e, sl); }
    if (it > 3) { float e; SEL8(e, Qd); w3 = bcastf(e, sl); }
    float crv;
    { float e; SEL8(e, c); crv = bcastf(e, sl); }

    // ---- scalar chain: dn = rsqrt(1-||w||^2); y_it = crv*dn ----
    float s2 = 1.f - w0 * w0 - w1 * w1 - w2 * w2 - w3 * w3;
    float dn = (it == 0) ? 1.f : __builtin_amdgcn_rsqf(s2);
    float yn = crv * dn;
    if (it == 0) { I0 = khat; y0v = yn; }
    if (it == 1) { I1 = khat; y1v = yn; L10 = w0; d1v = dn; }
    if (it == 2) { I2 = khat; y2v = yn; L20 = w0; L21 = w1; d2v = dn; }
    if (it == 3) { I3 = khat; y3v = yn; L30 = w0; L31 = w1; L32 = w2; d3v = dn; }
    if (it == 4) { I4 = khat; y4v = yn; L40 = w0; L41 = w1; L42 = w2; L43 = w3; d4v = dn; }

    // ---- orthogonalize new column; rank-1 residual update ----
    if (it < 4) {
      float qn0 = na.x,  qn1 = na.y,  qn2 = na.z,  qn3 = na.w;
      float qn4 = nbv.x, qn5 = nbv.y, qn6 = nbv.z, qn7 = nbv.w;
      if (it > 0) { ORTHO8(Qa, w0); }
      if (it > 1) { ORTHO8(Qb, w1); }
      if (it > 2) { ORTHO8(Qc, w2); }
      qn0 *= dn; qn1 *= dn; qn2 *= dn; qn3 *= dn;
      qn4 *= dn; qn5 *= dn; qn6 *= dn; qn7 *= dn;
      if (it == 0) { SETQ8(Qa); }
      if (it == 1) { SETQ8(Qb); }
      if (it == 2) { SETQ8(Qc); }
      if (it == 3) { SETQ8(Qd); }
      c0 = fmaf(-yn, qn0, c0); c1 = fmaf(-yn, qn1, c1);
      c2 = fmaf(-yn, qn2, c2); c3 = fmaf(-yn, qn3, c3);
      c4 = fmaf(-yn, qn4, c4); c5 = fmaf(-yn, qn5, c5);
      c6 = fmaf(-yn, qn6, c6); c7 = fmaf(-yn, qn7, c7);
    }
  } // it

  // ---- back-substitution (once) + epilogue ----
  float x4 = y4v * d4v;
  float x3 = (y3v - L43 * x4) * d3v;
  float x2 = (y2v - L32 * x3 - L42 * x4) * d2v;
  float x1 = (y1v - L21 * x2 - L31 * x3 - L41 * x4) * d1v;
  float x0 =  y0v - L10 * x1 - L20 * x2 - L30 * x3 - L40 * x4;

  if (lane < 5) {
    int It = I0; float xt = x0;
    if (lane == 1) { It = I1; xt = x1; }
    if (lane == 2) { It = I2; xt = x2; }
    if (lane == 3) { It = I3; xt = x3; }
    if (lane == 4) { It = I4; xt = x4; }
    coeffs[(long)It * NSIG + n] = xt;
  }
  float rec = x0 * DT[I0 * 64 + lane];
  rec = fmaf(x1, DT[I1 * 64 + lane], rec);
  rec = fmaf(x2, DT[I2 * 64 + lane], rec);
  rec = fmaf(x3, DT[I3 * 64 + lane], rec);
  rec = fmaf(x4, DT[I4 * 64 + lane], rec);
  const float d = rec - zv;
  const int offn = (n & 63) * 1024 + (n >> 11) * 32 + ((n >> 6) & 31);
  out0[lane * 65536 + offn] = zv + d;    // z + (z_dl - z), faithful
  return d * d;
}

__global__ __launch_bounds__(256, 4) void k_omp(
    const float* __restrict__ D, const float* __restrict__ G,
    const float* __restrict__ DT, const float* __restrict__ ST,
    float* __restrict__ out0, float* __restrict__ lossp,
    float* __restrict__ coeffs) {
  const int lane = threadIdx.x & 63;
  const int wid  = (blockIdx.x * 256 + threadIdx.x) >> 6;   // 0..8191
  const int sig0 = wid * 8;
  const float* Dp = D + 8 * lane;
  float lossacc = 0.f;

  // 2 batches of 4 signals; all state in named scalars (no arrays -> no
  // scratch/LDS demotion). Peak live ~110 VGPR, under the 128 cap from
  // __launch_bounds__(256,4).
  #pragma unroll 1
  for (int g = 0; g < 2; ++g) {
    const int base = sig0 + g * 4;
    float sv0 = ST[(base + 0) * 64 + lane];
    float sv1 = ST[(base + 1) * 64 + lane];
    float sv2 = ST[(base + 2) * 64 + lane];
    float sv3 = ST[(base + 3) * 64 + lane];

    DECL8Z(ca); DECL8Z(cb); DECL8Z(cc); DECL8Z(cd);

    #pragma unroll 2
    for (int r = 0; r < 64; ++r) {
      const float4 d0 = *reinterpret_cast<const float4*>(Dp + r * KAT);
      const float4 d1 = *reinterpret_cast<const float4*>(Dp + r * KAT + 4);
      const float s0 = bcastf(sv0, r);
      const float s1 = bcastf(sv1, r);
      const float s2 = bcastf(sv2, r);
      const float s3 = bcastf(sv3, r);
      FMA8(ca, s0); FMA8(cb, s1); FMA8(cc, s2); FMA8(cd, s3);
    }

    lossacc += omp_one(ca0, ca1, ca2, ca3, ca4, ca5, ca6, ca7,
                       G, DT, out0, coeffs, base + 0, lane, sv0);
    lossacc += omp_one(cb0, cb1, cb2, cb3, cb4, cb5, cb6, cb7,
                       G, DT, out0, coeffs, base + 1, lane, sv1);
    lossacc += omp_one(cc0, cc1, cc2, cc3, cc4, cc5, cc6, cc7,
                       G, DT, out0, coeffs, base + 2, lane, sv2);
    lossacc += omp_one(cd0, cd1, cd2, cd3, cd4, cd5, cd6, cd7,
                       G, DT, out0, coeffs, base + 3, lane, sv3);
  }

  #pragma unroll
  for (int off = 32; off > 0; off >>= 1) lossacc += __shfl_xor(lossacc, off);
  if (lane == 0) atomicAdd(lossp, lossacc * (1.25f / 4194304.f));
}

extern "C" void kernel_launch(void* const* d_in, const int* in_sizes, int n_in,
                              void* d_out, int out_size, void* d_ws, size_t ws_size,
                              hipStream_t stream) {
  const float* ze = (const float*)d_in[0];
  const float* D  = (const float*)d_in[1];
  float* out0 = (float*)d_out;
  float* lossp = out0 + 4194304;
  float* coeffs = out0 + 4194305;

  float* wsf = (float*)d_ws;
  float* G  = wsf;              // 262144 floats
  float* DT = wsf + 262144;     // 32768 floats
  float* ST = wsf + 294912;     // 4194304 floats

  // zero loss + coeffs (out0 is fully overwritten)
  (void)hipMemsetAsync((char*)d_out + 16777216ull, 0, 134217732ull, stream);

  hipLaunchKernelGGL(k_gram, dim3(1024), dim3(256), 0, stream, D, G, DT);
  hipLaunchKernelGGL(k_tr,   dim3(2048), dim3(256), 0, stream, ze, ST);
  hipLaunchKernelGGL(k_omp,  dim3(2048), dim3(256), 0, stream,
                     D, G, DT, ST, out0, lossp, coeffs);
}

// Round 9
// 219.872 us; speedup vs baseline: 3.5275x; 1.0085x over previous
//
#include <hip/hip_runtime.h>

#define NSIG  65536
#define KAT   512
#define CDIM  64

__device__ __forceinline__ float bcastf(float v, int l) {
  return __int_as_float(__builtin_amdgcn_readlane(__float_as_int(v), l));
}
__device__ __forceinline__ unsigned umaxu(unsigned a, unsigned b) {
  return a > b ? a : b;
}
__device__ __forceinline__ unsigned dppmax(unsigned v, const int ctrl) {
  switch (ctrl) {
    case 0xB1:  return umaxu(v, (unsigned)__builtin_amdgcn_mov_dpp((int)v, 0xB1, 0xF, 0xF, true));
    case 0x4E:  return umaxu(v, (unsigned)__builtin_amdgcn_mov_dpp((int)v, 0x4E, 0xF, 0xF, true));
    case 0x124: return umaxu(v, (unsigned)__builtin_amdgcn_mov_dpp((int)v, 0x124, 0xF, 0xF, true));
    default:    return umaxu(v, (unsigned)__builtin_amdgcn_mov_dpp((int)v, 0x128, 0xF, 0xF, true));
  }
}

// G = D^T D  [512][512]; DT[k][c] = D[c][k]
__global__ void k_gram(const float* __restrict__ D, float* __restrict__ G,
                       float* __restrict__ DT) {
  int tid = blockIdx.x * 256 + threadIdx.x;      // 262144 total
  int i = tid >> 9, j = tid & 511;
  float acc = 0.f;
  #pragma unroll 8
  for (int c = 0; c < CDIM; ++c) acc = fmaf(D[c * KAT + i], D[c * KAT + j], acc);
  G[tid] = acc;
  if (tid < KAT * CDIM) {
    int k = tid >> 6, c = tid & 63;
    DT[tid] = D[c * KAT + k];
  }
}

// ST[n][b] = z_e[b][n%64][n/2048][(n/64)%32]   (signal-major staging)
__global__ void k_tr(const float* __restrict__ ze, float* __restrict__ st) {
  __shared__ float tile[64][33];
  int cz = blockIdx.x >> 5;
  int h  = blockIdx.x & 31;
  int t  = threadIdx.x;
  #pragma unroll
  for (int q = 0; q < 8; ++q) {
    int idx = q * 256 + t;
    int b = idx >> 5, w = idx & 31;
    tile[b][w] = ze[b * 65536 + cz * 1024 + h * 32 + w];
  }
  __syncthreads();
  #pragma unroll
  for (int q = 0; q < 8; ++q) {
    int idx = q * 256 + t;
    int w = idx >> 6, b = idx & 63;
    st[(h * 2048 + w * 64 + cz) * 64 + b] = tile[b][w];
  }
}

// ---- all-scalar helpers ----
#define DECL8Z(p) float p##0=0.f,p##1=0.f,p##2=0.f,p##3=0.f,p##4=0.f,p##5=0.f,p##6=0.f,p##7=0.f
#define FMA8(p, sc)                                         \
  p##0 = fmaf(d0.x, sc, p##0); p##1 = fmaf(d0.y, sc, p##1); \
  p##2 = fmaf(d0.z, sc, p##2); p##3 = fmaf(d0.w, sc, p##3); \
  p##4 = fmaf(d1.x, sc, p##4); p##5 = fmaf(d1.y, sc, p##5); \
  p##6 = fmaf(d1.z, sc, p##6); p##7 = fmaf(d1.w, sc, p##7)
#define SEL8(e, p)                                          \
  e = p##0;                                                 \
  e = (jj == 1) ? p##1 : e; e = (jj == 2) ? p##2 : e;       \
  e = (jj == 3) ? p##3 : e; e = (jj == 4) ? p##4 : e;       \
  e = (jj == 5) ? p##5 : e; e = (jj == 6) ? p##6 : e;       \
  e = (jj == 7) ? p##7 : e

// One full OMP solve for one signal; cr in 8 scalar refs; Q0..Q2 in this
// wave's LDS slice (conflict-free layout), Q3 in registers.
__device__ __forceinline__ float omp_one(
    float& c0, float& c1, float& c2, float& c3,
    float& c4, float& c5, float& c6, float& c7,
    float* __restrict__ QW,            // this wave's LDS: [3][2][64] float4 = [3][512] float
    const float* __restrict__ G, const float* __restrict__ DT,
    float* __restrict__ out0, float* __restrict__ coeffs,
    int n, int lane, float zv) {
  int omega = 0xFF;
  int I0 = 0, I1 = 0, I2 = 0, I3 = 0, I4 = 0;
  float L10 = 0, L20 = 0, L21 = 0;
  float L30 = 0, L31 = 0, L32 = 0;
  float L40 = 0, L41 = 0, L42 = 0, L43 = 0;
  float d1v = 1.f, d2v = 1.f, d3v = 1.f, d4v = 1.f;
  float y0v = 0, y1v = 0, y2v = 0, y3v = 0, y4v = 0;
  DECL8Z(Qd);                                   // 4th column, registers

  float4* QW4 = reinterpret_cast<float4*>(QW);  // [3][2][64]

  #pragma unroll 1
  for (int it = 0; it < 5; ++it) {
    // ---- argmax of |cr|*omega: DPP reduce, first-index tie-break ----
    unsigned ab0 = (omega & 1)        ? (__float_as_uint(c0) & 0x7FFFFFFFu) : 0u;
    unsigned ab1 = ((omega >> 1) & 1) ? (__float_as_uint(c1) & 0x7FFFFFFFu) : 0u;
    unsigned ab2 = ((omega >> 2) & 1) ? (__float_as_uint(c2) & 0x7FFFFFFFu) : 0u;
    unsigned ab3 = ((omega >> 3) & 1) ? (__float_as_uint(c3) & 0x7FFFFFFFu) : 0u;
    unsigned ab4 = ((omega >> 4) & 1) ? (__float_as_uint(c4) & 0x7FFFFFFFu) : 0u;
    unsigned ab5 = ((omega >> 5) & 1) ? (__float_as_uint(c5) & 0x7FFFFFFFu) : 0u;
    unsigned ab6 = ((omega >> 6) & 1) ? (__float_as_uint(c6) & 0x7FFFFFFFu) : 0u;
    unsigned ab7 = ((omega >> 7) & 1) ? (__float_as_uint(c7) & 0x7FFFFFFFu) : 0u;
    unsigned la = umaxu(umaxu(umaxu(ab0, ab1), umaxu(ab2, ab3)),
                        umaxu(umaxu(ab4, ab5), umaxu(ab6, ab7)));
    unsigned rmax = la;
    rmax = dppmax(rmax, 0xB1);
    rmax = dppmax(rmax, 0x4E);
    rmax = dppmax(rmax, 0x124);
    rmax = dppmax(rmax, 0x128);
    unsigned gmu = umaxu(
        umaxu((unsigned)__builtin_amdgcn_readlane((int)rmax, 0),
              (unsigned)__builtin_amdgcn_readlane((int)rmax, 16)),
        umaxu((unsigned)__builtin_amdgcn_readlane((int)rmax, 32),
              (unsigned)__builtin_amdgcn_readlane((int)rmax, 48)));
    unsigned long long ball = __ballot(la == gmu);
    const int sl = __ffsll((long long)ball) - 1;   // lowest winning lane
    int jb = 7;
    jb = (ab6 == gmu) ? 6 : jb;
    jb = (ab5 == gmu) ? 5 : jb;
    jb = (ab4 == gmu) ? 4 : jb;
    jb = (ab3 == gmu) ? 3 : jb;
    jb = (ab2 == gmu) ? 2 : jb;
    jb = (ab1 == gmu) ? 1 : jb;
    jb = (ab0 == gmu) ? 0 : jb;
    const int jj = __builtin_amdgcn_readlane(jb, sl) & 7;
    const int khat = (sl << 3) | jj;
    if (lane == sl) omega &= ~(1 << jj);

    // ---- issue uniform-address LDS extractions of w_u = Q_u[khat] ----
    // float index within a column: ((a>>2)&1)*256 + (a>>3)*4 + (a&3)
    const int eoff = ((khat >> 2) & 1) * 256 + (khat >> 3) * 4 + (khat & 3);
    float w0 = 0.f, w1 = 0.f, w2 = 0.f, w3 = 0.f;
    if (it > 0) w0 = QW[eoff];
    if (it > 1) w1 = QW[512 + eoff];
    if (it > 2) w2 = QW[1024 + eoff];
    if (it > 3) { float e; SEL8(e, Qd); w3 = bcastf(e, sl); }

    // issue the new G row load (consumed after scalar chain)
    float4 na = {0, 0, 0, 0}, nbv = {0, 0, 0, 0};
    if (it < 4) {
      na  = *reinterpret_cast<const float4*>(G + khat * KAT + 8 * lane);
      nbv = *reinterpret_cast<const float4*>(G + khat * KAT + 8 * lane + 4);
    }

    // crv = cr[khat] (register select + broadcast, overlaps LDS latency)
    float crv;
    { float e; SEL8(e, c); crv = bcastf(e, sl); }

    // ---- scalar chain: dn = rsqrt(1-||w||^2); y_it = crv*dn ----
    float s2 = 1.f - w0 * w0 - w1 * w1 - w2 * w2 - w3 * w3;
    float dn = __builtin_amdgcn_rsqf(s2);          // rsq(1.0)==1.0 at it==0
    float yn = crv * dn;
    if (it == 0) { I0 = khat; y0v = yn; }
    if (it == 1) { I1 = khat; y1v = yn; L10 = w0; d1v = dn; }
    if (it == 2) { I2 = khat; y2v = yn; L20 = w0; L21 = w1; d2v = dn; }
    if (it == 3) { I3 = khat; y3v = yn; L30 = w0; L31 = w1; L32 = w2; d3v = dn; }
    if (it == 4) { I4 = khat; y4v = yn; L40 = w0; L41 = w1; L42 = w2; L43 = w3; d4v = dn; }

    // ---- orthogonalize new column; rank-1 residual update ----
    if (it < 4) {
      float qn0 = na.x,  qn1 = na.y,  qn2 = na.z,  qn3 = na.w;
      float qn4 = nbv.x, qn5 = nbv.y, qn6 = nbv.z, qn7 = nbv.w;
      if (it > 0) {
        float4 lo = QW4[0 * 128 + lane], hi = QW4[0 * 128 + 64 + lane];
        qn0 = fmaf(-w0, lo.x, qn0); qn1 = fmaf(-w0, lo.y, qn1);
        qn2 = fmaf(-w0, lo.z, qn2); qn3 = fmaf(-w0, lo.w, qn3);
        qn4 = fmaf(-w0, hi.x, qn4); qn5 = fmaf(-w0, hi.y, qn5);
        qn6 = fmaf(-w0, hi.z, qn6); qn7 = fmaf(-w0, hi.w, qn7);
      }
      if (it > 1) {
        float4 lo = QW4[1 * 128 + lane], hi = QW4[1 * 128 + 64 + lane];
        qn0 = fmaf(-w1, lo.x, qn0); qn1 = fmaf(-w1, lo.y, qn1);
        qn2 = fmaf(-w1, lo.z, qn2); qn3 = fmaf(-w1, lo.w, qn3);
        qn4 = fmaf(-w1, hi.x, qn4); qn5 = fmaf(-w1, hi.y, qn5);
        qn6 = fmaf(-w1, hi.z, qn6); qn7 = fmaf(-w1, hi.w, qn7);
      }
      if (it > 2) {
        float4 lo = QW4[2 * 128 + lane], hi = QW4[2 * 128 + 64 + lane];
        qn0 = fmaf(-w2, lo.x, qn0); qn1 = fmaf(-w2, lo.y, qn1);
        qn2 = fmaf(-w2, lo.z, qn2); qn3 = fmaf(-w2, lo.w, qn3);
        qn4 = fmaf(-w2, hi.x, qn4); qn5 = fmaf(-w2, hi.y, qn5);
        qn6 = fmaf(-w2, hi.z, qn6); qn7 = fmaf(-w2, hi.w, qn7);
      }
      qn0 *= dn; qn1 *= dn; qn2 *= dn; qn3 *= dn;
      qn4 *= dn; qn5 *= dn; qn6 *= dn; qn7 *= dn;
      if (it < 3) {
        QW4[it * 128 + lane]      = make_float4(qn0, qn1, qn2, qn3);
        QW4[it * 128 + 64 + lane] = make_float4(qn4, qn5, qn6, qn7);
      } else {
        Qd0 = qn0; Qd1 = qn1; Qd2 = qn2; Qd3 = qn3;
        Qd4 = qn4; Qd5 = qn5; Qd6 = qn6; Qd7 = qn7;
      }
      c0 = fmaf(-yn, qn0, c0); c1 = fmaf(-yn, qn1, c1);
      c2 = fmaf(-yn, qn2, c2); c3 = fmaf(-yn, qn3, c3);
      c4 = fmaf(-yn, qn4, c4); c5 = fmaf(-yn, qn5, c5);
      c6 = fmaf(-yn, qn6, c6); c7 = fmaf(-yn, qn7, c7);
    }
  } // it

  // ---- back-substitution (once) + epilogue ----
  float x4 = y4v * d4v;
  float x3 = (y3v - L43 * x4) * d3v;
  float x2 = (y2v - L32 * x3 - L42 * x4) * d2v;
  float x1 = (y1v - L21 * x2 - L31 * x3 - L41 * x4) * d1v;
  float x0 =  y0v - L10 * x1 - L20 * x2 - L30 * x3 - L40 * x4;

  if (lane < 5) {
    int It = I0; float xt = x0;
    if (lane == 1) { It = I1; xt = x1; }
    if (lane == 2) { It = I2; xt = x2; }
    if (lane == 3) { It = I3; xt = x3; }
    if (lane == 4) { It = I4; xt = x4; }
    coeffs[(long)It * NSIG + n] = xt;
  }
  float rec = x0 * DT[I0 * 64 + lane];
  rec = fmaf(x1, DT[I1 * 64 + lane], rec);
  rec = fmaf(x2, DT[I2 * 64 + lane], rec);
  rec = fmaf(x3, DT[I3 * 64 + lane], rec);
  rec = fmaf(x4, DT[I4 * 64 + lane], rec);
  const float d = rec - zv;
  const int offn = (n & 63) * 1024 + (n >> 11) * 32 + ((n >> 6) & 31);
  out0[lane * 65536 + offn] = zv + d;    // z + (z_dl - z), faithful
  return d * d;
}

__global__ __launch_bounds__(256, 4) void k_omp(
    const float* __restrict__ D, const float* __restrict__ G,
    const float* __restrict__ DT, const float* __restrict__ ST,
    float* __restrict__ out0, float* __restrict__ lossp,
    float* __restrict__ coeffs) {
  // per-wave Q columns 0..2: [wave][u][half][lane] float4 = 24 KB/block
  __shared__ float QL[4][3][512];
  const int wv   = threadIdx.x >> 6;
  const int lane = threadIdx.x & 63;
  const int wid  = (blockIdx.x * 256 + threadIdx.x) >> 6;   // 0..8191
  const int sig0 = wid * 8;
  const float* Dp = D + 8 * lane;
  float* QW = &QL[wv][0][0];
  float lossacc = 0.f;

  #pragma unroll 1
  for (int g = 0; g < 2; ++g) {
    const int base = sig0 + g * 4;
    float sv0 = ST[(base + 0) * 64 + lane];
    float sv1 = ST[(base + 1) * 64 + lane];
    float sv2 = ST[(base + 2) * 64 + lane];
    float sv3 = ST[(base + 3) * 64 + lane];

    DECL8Z(ca); DECL8Z(cb); DECL8Z(cc); DECL8Z(cd);

    #pragma unroll 2
    for (int r = 0; r < 64; ++r) {
      const float4 d0 = *reinterpret_cast<const float4*>(Dp + r * KAT);
      const float4 d1 = *reinterpret_cast<const float4*>(Dp + r * KAT + 4);
      const float s0 = bcastf(sv0, r);
      const float s1 = bcastf(sv1, r);
      const float s2 = bcastf(sv2, r);
      const float s3 = bcastf(sv3, r);
      FMA8(ca, s0); FMA8(cb, s1); FMA8(cc, s2); FMA8(cd, s3);
    }

    lossacc += omp_one(ca0, ca1, ca2, ca3, ca4, ca5, ca6, ca7,
                       QW, G, DT, out0, coeffs, base + 0, lane, sv0);
    lossacc += omp_one(cb0, cb1, cb2, cb3, cb4, cb5, cb6, cb7,
                       QW, G, DT, out0, coeffs, base + 1, lane, sv1);
    lossacc += omp_one(cc0, cc1, cc2, cc3, cc4, cc5, cc6, cc7,
                       QW, G, DT, out0, coeffs, base + 2, lane, sv2);
    lossacc += omp_one(cd0, cd1, cd2, cd3, cd4, cd5, cd6, cd7,
                       QW, G, DT, out0, coeffs, base + 3, lane, sv3);
  }

  #pragma unroll
  for (int off = 32; off > 0; off >>= 1) lossacc += __shfl_xor(lossacc, off);
  if (lane == 0) atomicAdd(lossp, lossacc * (1.25f / 4194304.f));
}

extern "C" void kernel_launch(void* const* d_in, const int* in_sizes, int n_in,
                              void* d_out, int out_size, void* d_ws, size_t ws_size,
                              hipStream_t stream) {
  const float* ze = (const float*)d_in[0];
  const float* D  = (const float*)d_in[1];
  float* out0 = (float*)d_out;
  float* lossp = out0 + 4194304;
  float* coeffs = out0 + 4194305;

  float* wsf = (float*)d_ws;
  float* G  = wsf;              // 262144 floats
  float* DT = wsf + 262144;     // 32768 floats
  float* ST = wsf + 294912;     // 4194304 floats

  // zero loss + coeffs (out0 is fully overwritten)
  (void)hipMemsetAsync((char*)d_out + 16777216ull, 0, 134217732ull, stream);

  hipLaunchKernelGGL(k_gram, dim3(1024), dim3(256), 0, stream, D, G, DT);
  hipLaunchKernelGGL(k_tr,   dim3(2048), dim3(256), 0, stream, ze, ST);
  hipLaunchKernelGGL(k_omp,  dim3(2048), dim3(256), 0, stream,
                     D, G, DT, ST, out0, lossp, coeffs);
}

// Round 10
// 190.341 us; speedup vs baseline: 4.0748x; 1.1551x over previous
//
#include <hip/hip_runtime.h>

#define NSIG  65536
#define KAT   512
#define CDIM  64

__device__ __forceinline__ float bcastf(float v, int l) {
  return __int_as_float(__builtin_amdgcn_readlane(__float_as_int(v), l));
}
__device__ __forceinline__ unsigned umaxu(unsigned a, unsigned b) {
  return a > b ? a : b;
}
__device__ __forceinline__ unsigned dppmax(unsigned v, const int ctrl) {
  switch (ctrl) {
    case 0xB1:  return umaxu(v, (unsigned)__builtin_amdgcn_mov_dpp((int)v, 0xB1, 0xF, 0xF, true));
    case 0x4E:  return umaxu(v, (unsigned)__builtin_amdgcn_mov_dpp((int)v, 0x4E, 0xF, 0xF, true));
    case 0x124: return umaxu(v, (unsigned)__builtin_amdgcn_mov_dpp((int)v, 0x124, 0xF, 0xF, true));
    default:    return umaxu(v, (unsigned)__builtin_amdgcn_mov_dpp((int)v, 0x128, 0xF, 0xF, true));
  }
}

// G = D^T D  [512][512]; DT[k][c] = D[c][k]
__global__ void k_gram(const float* __restrict__ D, float* __restrict__ G,
                       float* __restrict__ DT) {
  int tid = blockIdx.x * 256 + threadIdx.x;      // 262144 total
  int i = tid >> 9, j = tid & 511;
  float acc = 0.f;
  #pragma unroll 8
  for (int c = 0; c < CDIM; ++c) acc = fmaf(D[c * KAT + i], D[c * KAT + j], acc);
  G[tid] = acc;
  if (tid < KAT * CDIM) {
    int k = tid >> 6, c = tid & 63;
    DT[tid] = D[c * KAT + k];
  }
}

// ST[n][b] = z_e[b][n%64][n/2048][(n/64)%32]   (signal-major staging)
__global__ void k_tr(const float* __restrict__ ze, float* __restrict__ st) {
  __shared__ float tile[64][33];
  int cz = blockIdx.x >> 5;
  int h  = blockIdx.x & 31;
  int t  = threadIdx.x;
  #pragma unroll
  for (int q = 0; q < 8; ++q) {
    int idx = q * 256 + t;
    int b = idx >> 5, w = idx & 31;
    tile[b][w] = ze[b * 65536 + cz * 1024 + h * 32 + w];
  }
  __syncthreads();
  #pragma unroll
  for (int q = 0; q < 8; ++q) {
    int idx = q * 256 + t;
    int w = idx >> 6, b = idx & 63;
    st[(h * 2048 + w * 64 + cz) * 64 + b] = tile[b][w];
  }
}

// ---- all-scalar helpers ----
#define DECL8Z(p) float p##0=0.f,p##1=0.f,p##2=0.f,p##3=0.f,p##4=0.f,p##5=0.f,p##6=0.f,p##7=0.f
#define FMA8(p, sc)                                         \
  p##0 = fmaf(d0.x, sc, p##0); p##1 = fmaf(d0.y, sc, p##1); \
  p##2 = fmaf(d0.z, sc, p##2); p##3 = fmaf(d0.w, sc, p##3); \
  p##4 = fmaf(d1.x, sc, p##4); p##5 = fmaf(d1.y, sc, p##5); \
  p##6 = fmaf(d1.z, sc, p##6); p##7 = fmaf(d1.w, sc, p##7)
#define SEL8(e, p)                                          \
  e = p##0;                                                 \
  e = (jj == 1) ? p##1 : e; e = (jj == 2) ? p##2 : e;       \
  e = (jj == 3) ? p##3 : e; e = (jj == 4) ? p##4 : e;       \
  e = (jj == 5) ? p##5 : e; e = (jj == 6) ? p##6 : e;       \
  e = (jj == 7) ? p##7 : e

// One full OMP solve for one signal; cr in 8 scalar refs; Q0..Q2 in this
// wave's LDS slice, Q3 in registers. it-loop FULLY UNROLLED (all guards
// fold at compile time). Returns per-lane residual d = rec - zv.
__device__ __forceinline__ float omp_one(
    float& c0, float& c1, float& c2, float& c3,
    float& c4, float& c5, float& c6, float& c7,
    float* __restrict__ QW,            // [3][2][64] float4 = [3][512] float
    const float* __restrict__ G, const float* __restrict__ DT,
    float* __restrict__ coeffs,
    int n, int lane, float zv) {
  int omega = 0xFF;
  int I0 = 0, I1 = 0, I2 = 0, I3 = 0, I4 = 0;
  float L10 = 0, L20 = 0, L21 = 0;
  float L30 = 0, L31 = 0, L32 = 0;
  float L40 = 0, L41 = 0, L42 = 0, L43 = 0;
  float d1v = 1.f, d2v = 1.f, d3v = 1.f, d4v = 1.f;
  float y0v = 0, y1v = 0, y2v = 0, y3v = 0, y4v = 0;
  DECL8Z(Qd);                                   // 4th column, registers

  float4* QW4 = reinterpret_cast<float4*>(QW);  // [3][2][64]

  #pragma unroll
  for (int it = 0; it < 5; ++it) {
    // ---- argmax of |cr|*omega: DPP reduce, first-index tie-break ----
    unsigned ab0 = (omega & 1)        ? (__float_as_uint(c0) & 0x7FFFFFFFu) : 0u;
    unsigned ab1 = ((omega >> 1) & 1) ? (__float_as_uint(c1) & 0x7FFFFFFFu) : 0u;
    unsigned ab2 = ((omega >> 2) & 1) ? (__float_as_uint(c2) & 0x7FFFFFFFu) : 0u;
    unsigned ab3 = ((omega >> 3) & 1) ? (__float_as_uint(c3) & 0x7FFFFFFFu) : 0u;
    unsigned ab4 = ((omega >> 4) & 1) ? (__float_as_uint(c4) & 0x7FFFFFFFu) : 0u;
    unsigned ab5 = ((omega >> 5) & 1) ? (__float_as_uint(c5) & 0x7FFFFFFFu) : 0u;
    unsigned ab6 = ((omega >> 6) & 1) ? (__float_as_uint(c6) & 0x7FFFFFFFu) : 0u;
    unsigned ab7 = ((omega >> 7) & 1) ? (__float_as_uint(c7) & 0x7FFFFFFFu) : 0u;
    unsigned la = umaxu(umaxu(umaxu(ab0, ab1), umaxu(ab2, ab3)),
                        umaxu(umaxu(ab4, ab5), umaxu(ab6, ab7)));
    unsigned rmax = la;
    rmax = dppmax(rmax, 0xB1);
    rmax = dppmax(rmax, 0x4E);
    rmax = dppmax(rmax, 0x124);
    rmax = dppmax(rmax, 0x128);
    unsigned gmu = umaxu(
        umaxu((unsigned)__builtin_amdgcn_readlane((int)rmax, 0),
              (unsigned)__builtin_amdgcn_readlane((int)rmax, 16)),
        umaxu((unsigned)__builtin_amdgcn_readlane((int)rmax, 32),
              (unsigned)__builtin_amdgcn_readlane((int)rmax, 48)));
    unsigned long long ball = __ballot(la == gmu);
    const int sl = __ffsll((long long)ball) - 1;   // lowest winning lane
    int jb = 7;
    jb = (ab6 == gmu) ? 6 : jb;
    jb = (ab5 == gmu) ? 5 : jb;
    jb = (ab4 == gmu) ? 4 : jb;
    jb = (ab3 == gmu) ? 3 : jb;
    jb = (ab2 == gmu) ? 2 : jb;
    jb = (ab1 == gmu) ? 1 : jb;
    jb = (ab0 == gmu) ? 0 : jb;
    const int jj = __builtin_amdgcn_readlane(jb, sl) & 7;
    const int khat = (sl << 3) | jj;
    if (lane == sl) omega &= ~(1 << jj);

    // ---- uniform-address LDS extractions of w_u = Q_u[khat] ----
    const int eoff = ((khat >> 2) & 1) * 256 + (khat >> 3) * 4 + (khat & 3);
    float w0 = 0.f, w1 = 0.f, w2 = 0.f, w3 = 0.f;
    if (it > 0) w0 = QW[eoff];
    if (it > 1) w1 = QW[512 + eoff];
    if (it > 2) w2 = QW[1024 + eoff];
    if (it > 3) { float e; SEL8(e, Qd); w3 = bcastf(e, sl); }

    // new G row load (consumed after scalar chain)
    float4 na = {0, 0, 0, 0}, nbv = {0, 0, 0, 0};
    if (it < 4) {
      na  = *reinterpret_cast<const float4*>(G + khat * KAT + 8 * lane);
      nbv = *reinterpret_cast<const float4*>(G + khat * KAT + 8 * lane + 4);
    }

    // crv = cr[khat] (register select + broadcast, overlaps LDS latency)
    float crv;
    { float e; SEL8(e, c); crv = bcastf(e, sl); }

    // ---- scalar chain: dn = rsqrt(1-||w||^2); y_it = crv*dn ----
    float s2 = 1.f - w0 * w0 - w1 * w1 - w2 * w2 - w3 * w3;
    float dn = __builtin_amdgcn_rsqf(s2);          // rsq(1.0)==1.0 at it==0
    float yn = crv * dn;
    if (it == 0) { I0 = khat; y0v = yn; }
    if (it == 1) { I1 = khat; y1v = yn; L10 = w0; d1v = dn; }
    if (it == 2) { I2 = khat; y2v = yn; L20 = w0; L21 = w1; d2v = dn; }
    if (it == 3) { I3 = khat; y3v = yn; L30 = w0; L31 = w1; L32 = w2; d3v = dn; }
    if (it == 4) { I4 = khat; y4v = yn; L40 = w0; L41 = w1; L42 = w2; L43 = w3; d4v = dn; }

    // ---- orthogonalize new column; rank-1 residual update ----
    if (it < 4) {
      float qn0 = na.x,  qn1 = na.y,  qn2 = na.z,  qn3 = na.w;
      float qn4 = nbv.x, qn5 = nbv.y, qn6 = nbv.z, qn7 = nbv.w;
      if (it > 0) {
        float4 lo = QW4[0 * 128 + lane], hi = QW4[0 * 128 + 64 + lane];
        qn0 = fmaf(-w0, lo.x, qn0); qn1 = fmaf(-w0, lo.y, qn1);
        qn2 = fmaf(-w0, lo.z, qn2); qn3 = fmaf(-w0, lo.w, qn3);
        qn4 = fmaf(-w0, hi.x, qn4); qn5 = fmaf(-w0, hi.y, qn5);
        qn6 = fmaf(-w0, hi.z, qn6); qn7 = fmaf(-w0, hi.w, qn7);
      }
      if (it > 1) {
        float4 lo = QW4[1 * 128 + lane], hi = QW4[1 * 128 + 64 + lane];
        qn0 = fmaf(-w1, lo.x, qn0); qn1 = fmaf(-w1, lo.y, qn1);
        qn2 = fmaf(-w1, lo.z, qn2); qn3 = fmaf(-w1, lo.w, qn3);
        qn4 = fmaf(-w1, hi.x, qn4); qn5 = fmaf(-w1, hi.y, qn5);
        qn6 = fmaf(-w1, hi.z, qn6); qn7 = fmaf(-w1, hi.w, qn7);
      }
      if (it > 2) {
        float4 lo = QW4[2 * 128 + lane], hi = QW4[2 * 128 + 64 + lane];
        qn0 = fmaf(-w2, lo.x, qn0); qn1 = fmaf(-w2, lo.y, qn1);
        qn2 = fmaf(-w2, lo.z, qn2); qn3 = fmaf(-w2, lo.w, qn3);
        qn4 = fmaf(-w2, hi.x, qn4); qn5 = fmaf(-w2, hi.y, qn5);
        qn6 = fmaf(-w2, hi.z, qn6); qn7 = fmaf(-w2, hi.w, qn7);
      }
      qn0 *= dn; qn1 *= dn; qn2 *= dn; qn3 *= dn;
      qn4 *= dn; qn5 *= dn; qn6 *= dn; qn7 *= dn;
      if (it < 3) {
        QW4[it * 128 + lane]      = make_float4(qn0, qn1, qn2, qn3);
        QW4[it * 128 + 64 + lane] = make_float4(qn4, qn5, qn6, qn7);
      } else {
        Qd0 = qn0; Qd1 = qn1; Qd2 = qn2; Qd3 = qn3;
        Qd4 = qn4; Qd5 = qn5; Qd6 = qn6; Qd7 = qn7;
      }
      c0 = fmaf(-yn, qn0, c0); c1 = fmaf(-yn, qn1, c1);
      c2 = fmaf(-yn, qn2, c2); c3 = fmaf(-yn, qn3, c3);
      c4 = fmaf(-yn, qn4, c4); c5 = fmaf(-yn, qn5, c5);
      c6 = fmaf(-yn, qn6, c6); c7 = fmaf(-yn, qn7, c7);
    }
  } // it

  // ---- back-substitution (once) + epilogue ----
  float x4 = y4v * d4v;
  float x3 = (y3v - L43 * x4) * d3v;
  float x2 = (y2v - L32 * x3 - L42 * x4) * d2v;
  float x1 = (y1v - L21 * x2 - L31 * x3 - L41 * x4) * d1v;
  float x0 =  y0v - L10 * x1 - L20 * x2 - L30 * x3 - L40 * x4;

  if (lane < 5) {
    int It = I0; float xt = x0;
    if (lane == 1) { It = I1; xt = x1; }
    if (lane == 2) { It = I2; xt = x2; }
    if (lane == 3) { It = I3; xt = x3; }
    if (lane == 4) { It = I4; xt = x4; }
    coeffs[(long)It * NSIG + n] = xt;
  }
  float rec = x0 * DT[I0 * 64 + lane];
  rec = fmaf(x1, DT[I1 * 64 + lane], rec);
  rec = fmaf(x2, DT[I2 * 64 + lane], rec);
  rec = fmaf(x3, DT[I3 * 64 + lane], rec);
  rec = fmaf(x4, DT[I4 * 64 + lane], rec);
  return rec - zv;                       // d = z_dl - z (per-lane component)
}

__global__ __launch_bounds__(256) void k_omp(
    const float* __restrict__ D, const float* __restrict__ G,
    const float* __restrict__ DT, const float* __restrict__ ST,
    float* __restrict__ out0, float* __restrict__ lossp,
    float* __restrict__ coeffs) {
  // per-wave Q columns 0..2: [wave][u][half][lane] float4 = 24 KB/block
  __shared__ float QL[4][3][512];
  const int wv   = threadIdx.x >> 6;
  const int lane = threadIdx.x & 63;
  const int wid  = (blockIdx.x * 256 + threadIdx.x) >> 6;   // 0..8191
  // strided signal mapping: n_j = c + 512*w3 + 64*j  (j = 0..7) makes each
  // lane's 8 out0 values consecutive -> single 32B store, no write amp.
  const int cc = wid >> 7;          // 0..63   (= n & 63)
  const int w3 = wid & 127;
  const int nbase = cc + 512 * w3;
  const float* Dp = D + 8 * lane;
  float* QW = &QL[wv][0][0];
  float lossacc = 0.f;
  float o0, o1, o2, o3, o4, o5, o6, o7;  // out0 values for j=0..7

  #pragma unroll 1
  for (int g = 0; g < 2; ++g) {
    const int n0 = nbase + 64 * (g * 4 + 0);
    const int n1 = nbase + 64 * (g * 4 + 1);
    const int n2 = nbase + 64 * (g * 4 + 2);
    const int n3 = nbase + 64 * (g * 4 + 3);
    float sv0 = ST[n0 * 64 + lane];
    float sv1 = ST[n1 * 64 + lane];
    float sv2 = ST[n2 * 64 + lane];
    float sv3 = ST[n3 * 64 + lane];

    DECL8Z(ca); DECL8Z(cb); DECL8Z(cc2); DECL8Z(cd);

    #pragma unroll 2
    for (int r = 0; r < 64; ++r) {
      const float4 d0 = *reinterpret_cast<const float4*>(Dp + r * KAT);
      const float4 d1 = *reinterpret_cast<const float4*>(Dp + r * KAT + 4);
      const float s0 = bcastf(sv0, r);
      const float s1 = bcastf(sv1, r);
      const float s2 = bcastf(sv2, r);
      const float s3 = bcastf(sv3, r);
      FMA8(ca, s0); FMA8(cb, s1); FMA8(cc2, s2); FMA8(cd, s3);
    }

    float da = omp_one(ca0, ca1, ca2, ca3, ca4, ca5, ca6, ca7,
                       QW, G, DT, coeffs, n0, lane, sv0);
    lossacc = fmaf(da, da, lossacc);
    float db = omp_one(cb0, cb1, cb2, cb3, cb4, cb5, cb6, cb7,
                       QW, G, DT, coeffs, n1, lane, sv1);
    lossacc = fmaf(db, db, lossacc);
    float dc = omp_one(cc20, cc21, cc22, cc23, cc24, cc25, cc26, cc27,
                       QW, G, DT, coeffs, n2, lane, sv2);
    lossacc = fmaf(dc, dc, lossacc);
    float dd = omp_one(cd0, cd1, cd2, cd3, cd4, cd5, cd6, cd7,
                       QW, G, DT, coeffs, n3, lane, sv3);
    lossacc = fmaf(dd, dd, lossacc);

    if (g == 0) { o0 = sv0 + da; o1 = sv1 + db; o2 = sv2 + dc; o3 = sv3 + dd; }
    else        { o4 = sv0 + da; o5 = sv1 + db; o6 = sv2 + dc; o7 = sv3 + dd; }
  }

  // out0: 8 consecutive floats per lane (32B-aligned), two dwordx4 stores
  const int obase = lane * 65536 + cc * 1024 + (w3 >> 2) * 32 + (w3 & 3) * 8;
  *reinterpret_cast<float4*>(out0 + obase)     = make_float4(o0, o1, o2, o3);
  *reinterpret_cast<float4*>(out0 + obase + 4) = make_float4(o4, o5, o6, o7);

  #pragma unroll
  for (int off = 32; off > 0; off >>= 1) lossacc += __shfl_xor(lossacc, off);
  if (lane == 0) atomicAdd(lossp, lossacc * (1.25f / 4194304.f));
}

extern "C" void kernel_launch(void* const* d_in, const int* in_sizes, int n_in,
                              void* d_out, int out_size, void* d_ws, size_t ws_size,
                              hipStream_t stream) {
  const float* ze = (const float*)d_in[0];
  const float* D  = (const float*)d_in[1];
  float* out0 = (float*)d_out;
  float* lossp = out0 + 4194304;
  float* coeffs = out0 + 4194305;

  float* wsf = (float*)d_ws;
  float* G  = wsf;              // 262144 floats
  float* DT = wsf + 262144;     // 32768 floats
  float* ST = wsf + 294912;     // 4194304 floats

  // zero loss + coeffs (out0 is fully overwritten)
  (void)hipMemsetAsync((char*)d_out + 16777216ull, 0, 134217732ull, stream);

  hipLaunchKernelGGL(k_gram, dim3(1024), dim3(256), 0, stream, D, G, DT);
  hipLaunchKernelGGL(k_tr,   dim3(2048), dim3(256), 0, stream, ze, ST);
  hipLaunchKernelGGL(k_omp,  dim3(2048), dim3(256), 0, stream,
                     D, G, DT, ST, out0, lossp, coeffs);
}